// Round 1
// baseline (2295.114 us; speedup 1.0000x reference)
//
#include <hip/hip_runtime.h>

#define NN 50000
#define NE 800000
#define EPSB 1e-5f
#define SLOPE 0.01f

// workspace layout (float offsets)
#define W_NRM   0
#define W_DIS   800000     // deg then dis, N floats
#define W_SUM1  850000     // 128
#define W_SQ1   850128     // 128
#define W_SUM2  850256     // 64
#define W_SQ2   850320     // 64
#define W_H1    851024     // N*128
#define W_O1    7251024    // N*128
#define W_H2    851024     // reuse H1 (dead after scatter1) N*64
// O2 lives in d_out

__global__ void k_deg(const int* __restrict__ col, const float* __restrict__ w,
                      float* __restrict__ deg) {
  int e = blockIdx.x * 256 + threadIdx.x;
  if (e < NE) atomicAdd(&deg[col[e]], w[e]);
}

__global__ void k_dis(float* deg_dis) {
  int i = blockIdx.x * 256 + threadIdx.x;
  if (i < NN) deg_dis[i] = rsqrtf(deg_dis[i] + 1.0f);  // +1 = self-loop weight
}

__global__ void k_norm(const int* __restrict__ adj, const float* __restrict__ w,
                       const float* __restrict__ dis, float* __restrict__ nrm) {
  int e = blockIdx.x * 256 + threadIdx.x;
  if (e < NE) {
    int r = adj[e], c = adj[NE + e];
    nrm[e] = dis[r] * w[e] * dis[c];
  }
}

// GEMM1: H[N,128] = X[N,128] @ W1[128,128]; 64-row tile, thread = 4 rows x 8 cols
__global__ __launch_bounds__(256) void k_gemm1(const float* __restrict__ X,
                                               const float* __restrict__ W1,
                                               float* __restrict__ H) {
  __shared__ float xs[64 * 132];
  int tid = threadIdx.x;
  int row0 = blockIdx.x * 64;
  for (int i = tid; i < 64 * 32; i += 256) {
    int r = i >> 5, k4 = i & 31;
    float4 v = (row0 + r < NN) ? ((const float4*)X)[(size_t)(row0 + r) * 32 + k4]
                               : make_float4(0.f, 0.f, 0.f, 0.f);
    *(float4*)&xs[r * 132 + k4 * 4] = v;
  }
  __syncthreads();
  int cg = tid & 15;   // 16 col groups * 8 cols = 128
  int rg = tid >> 4;   // 16 row groups * 4 rows = 64
  int f0 = cg * 8, r0 = rg * 4;
  float acc[4][8];
#pragma unroll
  for (int a = 0; a < 4; ++a)
#pragma unroll
    for (int b = 0; b < 8; ++b) acc[a][b] = 0.f;
  const float4* W4 = (const float4*)W1;
#pragma unroll 4
  for (int k = 0; k < 128; ++k) {
    float4 w0 = W4[k * 32 + (f0 >> 2)];
    float4 w1 = W4[k * 32 + (f0 >> 2) + 1];
    float wv[8] = {w0.x, w0.y, w0.z, w0.w, w1.x, w1.y, w1.z, w1.w};
    float xv[4];
#pragma unroll
    for (int a = 0; a < 4; ++a) xv[a] = xs[(r0 + a) * 132 + k];
#pragma unroll
    for (int a = 0; a < 4; ++a)
#pragma unroll
      for (int b = 0; b < 8; ++b) acc[a][b] += xv[a] * wv[b];
  }
#pragma unroll
  for (int a = 0; a < 4; ++a) {
    int r = row0 + r0 + a;
    if (r < NN) {
      float4* H4 = (float4*)&H[(size_t)r * 128 + f0];
      H4[0] = make_float4(acc[a][0], acc[a][1], acc[a][2], acc[a][3]);
      H4[1] = make_float4(acc[a][4], acc[a][5], acc[a][6], acc[a][7]);
    }
  }
}

// O1[i,f] = b1[f] + H1[i,f]*dis[i]^2   (self-loop contribution + bias)
__global__ void k_self1(const float* __restrict__ H, const float* __restrict__ dis,
                        const float* __restrict__ b1, float* __restrict__ O) {
  int i = blockIdx.x * 256 + threadIdx.x;   // over NN*32 float4s
  int row = i >> 5, f4 = i & 31;
  float d = dis[row];
  float d2 = d * d;
  float4 h = ((const float4*)H)[i];
  float4 b = ((const float4*)b1)[f4];
  float4 o;
  o.x = fmaf(h.x, d2, b.x);
  o.y = fmaf(h.y, d2, b.y);
  o.z = fmaf(h.z, d2, b.z);
  o.w = fmaf(h.w, d2, b.w);
  ((float4*)O)[i] = o;
}

__global__ void k_scat1(const int* __restrict__ adj, const float* __restrict__ nrm,
                        const float* __restrict__ H, float* __restrict__ O) {
  int t = blockIdx.x * 256 + threadIdx.x;   // NE * 32 threads
  int e = t >> 5, f4 = t & 31;
  int r = adj[e], c = adj[NE + e];
  float nm = nrm[e];
  float4 h = ((const float4*)H)[(size_t)r * 32 + f4];
  float* o = &O[(size_t)c * 128 + f4 * 4];
  atomicAdd(o + 0, h.x * nm);
  atomicAdd(o + 1, h.y * nm);
  atomicAdd(o + 2, h.z * nm);
  atomicAdd(o + 3, h.w * nm);
}

__global__ void k_stats(const float* __restrict__ X, float* __restrict__ sum,
                        float* __restrict__ sq, int C) {
  int f = threadIdx.x & (C - 1);
  int rg = threadIdx.x / C;
  int nrg = 256 / C;
  float s = 0.f, ss = 0.f;
  for (int r = blockIdx.x * nrg + rg; r < NN; r += gridDim.x * nrg) {
    float v = X[(size_t)r * C + f];
    s += v;
    ss += v * v;
  }
  __shared__ float ls[256], lss[256];
  ls[threadIdx.x] = s;
  lss[threadIdx.x] = ss;
  __syncthreads();
  if (rg == 0) {
    for (int g = 1; g < nrg; ++g) { s += ls[g * C + f]; ss += lss[g * C + f]; }
    atomicAdd(&sum[f], s);
    atomicAdd(&sq[f], ss);
  }
}

// GEMM2: H2[N,64] = leaky(BN1(O1)) @ W2[128,64]; BN+LeakyReLU fused into tile load
__global__ __launch_bounds__(256) void k_gemm2(const float* __restrict__ O1,
                                               const float* __restrict__ W2,
                                               const float* __restrict__ sum1,
                                               const float* __restrict__ sq1,
                                               const float* __restrict__ g1,
                                               const float* __restrict__ be1,
                                               float* __restrict__ H2) {
  __shared__ float xs[64 * 132];
  __shared__ float a1s[128], c1s[128];
  int tid = threadIdx.x;
  if (tid < 128) {
    float mu = sum1[tid] * (1.0f / NN);
    float var = sq1[tid] * (1.0f / NN) - mu * mu;
    float a = g1[tid] * rsqrtf(var + EPSB);
    a1s[tid] = a;
    c1s[tid] = be1[tid] - mu * a;
  }
  __syncthreads();
  int row0 = blockIdx.x * 64;
  for (int i = tid; i < 64 * 32; i += 256) {
    int r = i >> 5, k4 = i & 31;
    float4 v = (row0 + r < NN) ? ((const float4*)O1)[(size_t)(row0 + r) * 32 + k4]
                               : make_float4(0.f, 0.f, 0.f, 0.f);
    float4 a = *(const float4*)&a1s[k4 * 4];
    float4 c = *(const float4*)&c1s[k4 * 4];
    float4 y;
    y.x = fmaf(a.x, v.x, c.x);
    y.y = fmaf(a.y, v.y, c.y);
    y.z = fmaf(a.z, v.z, c.z);
    y.w = fmaf(a.w, v.w, c.w);
    y.x = y.x >= 0.f ? y.x : SLOPE * y.x;
    y.y = y.y >= 0.f ? y.y : SLOPE * y.y;
    y.z = y.z >= 0.f ? y.z : SLOPE * y.z;
    y.w = y.w >= 0.f ? y.w : SLOPE * y.w;
    *(float4*)&xs[r * 132 + k4 * 4] = y;
  }
  __syncthreads();
  int cg = tid & 7;   // 8 col groups * 8 cols = 64
  int rg = tid >> 3;  // 32 row groups * 2 rows = 64
  int f0 = cg * 8, r0 = rg * 2;
  float acc[2][8];
#pragma unroll
  for (int a = 0; a < 2; ++a)
#pragma unroll
    for (int b = 0; b < 8; ++b) acc[a][b] = 0.f;
  const float4* W4 = (const float4*)W2;
#pragma unroll 4
  for (int k = 0; k < 128; ++k) {
    float4 w0 = W4[k * 16 + (f0 >> 2)];
    float4 w1 = W4[k * 16 + (f0 >> 2) + 1];
    float wv[8] = {w0.x, w0.y, w0.z, w0.w, w1.x, w1.y, w1.z, w1.w};
    float x0 = xs[(r0 + 0) * 132 + k];
    float x1 = xs[(r0 + 1) * 132 + k];
#pragma unroll
    for (int b = 0; b < 8; ++b) {
      acc[0][b] += x0 * wv[b];
      acc[1][b] += x1 * wv[b];
    }
  }
#pragma unroll
  for (int a = 0; a < 2; ++a) {
    int r = row0 + r0 + a;
    if (r < NN) {
      float4* H4 = (float4*)&H2[(size_t)r * 64 + f0];
      H4[0] = make_float4(acc[a][0], acc[a][1], acc[a][2], acc[a][3]);
      H4[1] = make_float4(acc[a][4], acc[a][5], acc[a][6], acc[a][7]);
    }
  }
}

__global__ void k_self2(const float* __restrict__ H, const float* __restrict__ dis,
                        const float* __restrict__ b2, float* __restrict__ O) {
  int i = blockIdx.x * 256 + threadIdx.x;  // over NN*16 float4s
  int row = i >> 4, f4 = i & 15;
  float d = dis[row];
  float d2 = d * d;
  float4 h = ((const float4*)H)[i];
  float4 b = ((const float4*)b2)[f4];
  float4 o;
  o.x = fmaf(h.x, d2, b.x);
  o.y = fmaf(h.y, d2, b.y);
  o.z = fmaf(h.z, d2, b.z);
  o.w = fmaf(h.w, d2, b.w);
  ((float4*)O)[i] = o;
}

__global__ void k_scat2(const int* __restrict__ adj, const float* __restrict__ nrm,
                        const float* __restrict__ H, float* __restrict__ O) {
  int t = blockIdx.x * 256 + threadIdx.x;  // NE * 16 threads
  int e = t >> 4, f4 = t & 15;
  int r = adj[e], c = adj[NE + e];
  float nm = nrm[e];
  float4 h = ((const float4*)H)[(size_t)r * 16 + f4];
  float* o = &O[(size_t)c * 64 + f4 * 4];
  atomicAdd(o + 0, h.x * nm);
  atomicAdd(o + 1, h.y * nm);
  atomicAdd(o + 2, h.z * nm);
  atomicAdd(o + 3, h.w * nm);
}

__global__ void k_final(float* __restrict__ O, const float* __restrict__ sum2,
                        const float* __restrict__ sq2, const float* __restrict__ g2,
                        const float* __restrict__ be2) {
  int i = blockIdx.x * 256 + threadIdx.x;
  if (i < NN * 64) {
    int f = i & 63;
    float mu = sum2[f] * (1.0f / NN);
    float var = sq2[f] * (1.0f / NN) - mu * mu;
    float a = g2[f] * rsqrtf(var + EPSB);
    float c = be2[f] - mu * a;
    O[i] = fmaf(a, O[i], c);
  }
}

extern "C" void kernel_launch(void* const* d_in, const int* in_sizes, int n_in,
                              void* d_out, int out_size, void* d_ws, size_t ws_size,
                              hipStream_t stream) {
  const int* adj = (const int*)d_in[0];
  const float* w = (const float*)d_in[1];
  const float* X = (const float*)d_in[2];
  const float* W1 = (const float*)d_in[3];
  const float* b1 = (const float*)d_in[4];
  const float* g1 = (const float*)d_in[5];
  const float* be1 = (const float*)d_in[6];
  const float* W2 = (const float*)d_in[7];
  const float* b2 = (const float*)d_in[8];
  const float* g2 = (const float*)d_in[9];
  const float* be2 = (const float*)d_in[10];
  float* ws = (float*)d_ws;
  float* out = (float*)d_out;

  float* nrm = ws + W_NRM;
  float* dis = ws + W_DIS;
  float* sum1 = ws + W_SUM1;
  float* sq1 = ws + W_SQ1;
  float* sum2 = ws + W_SUM2;
  float* sq2 = ws + W_SQ2;
  float* H1 = ws + W_H1;
  float* O1 = ws + W_O1;
  float* H2 = ws + W_H2;

  // zero deg (reused as dis) + all stats in one contiguous memset
  hipMemsetAsync(dis, 0, 51024 * sizeof(float), stream);

  k_deg<<<(NE + 255) / 256, 256, 0, stream>>>(adj + NE, w, dis);
  k_dis<<<(NN + 255) / 256, 256, 0, stream>>>(dis);
  k_norm<<<NE / 256, 256, 0, stream>>>(adj, w, dis, nrm);

  k_gemm1<<<(NN + 63) / 64, 256, 0, stream>>>(X, W1, H1);
  k_self1<<<NN * 32 / 256, 256, 0, stream>>>(H1, dis, b1, O1);
  k_scat1<<<NE * 32 / 256, 256, 0, stream>>>(adj, nrm, H1, O1);
  k_stats<<<512, 256, 0, stream>>>(O1, sum1, sq1, 128);

  k_gemm2<<<(NN + 63) / 64, 256, 0, stream>>>(O1, W2, sum1, sq1, g1, be1, H2);
  k_self2<<<NN * 16 / 256, 256, 0, stream>>>(H2, dis, b2, out);
  k_scat2<<<NE * 16 / 256, 256, 0, stream>>>(adj, nrm, H2, out);
  k_stats<<<512, 256, 0, stream>>>(out, sum2, sq2, 64);
  k_final<<<NN * 64 / 256, 256, 0, stream>>>(out, sum2, sq2, g2, be2);
}

// Round 2
// 543.914 us; speedup vs baseline: 4.2196x; 4.2196x over previous
//
#include <hip/hip_runtime.h>

#define NN 50000
#define NE 800000
#define EPSB 1e-5f
#define SLOPE 0.01f

// workspace layout (4-byte element offsets)
#define W_SEDGE 0          // (NE+NN) int2 = 1,700,000 slots
#define W_OFF   1700000    // NN+1 ints
#define W_POS   1750432    // NN ints (aliases cnt)
#define W_DIS   1800432    // NN floats (aliases deg)
#define W_SUM1  1850432    // 128
#define W_SQ1   1850560    // 128
#define W_SUM2  1850688    // 64
#define W_SQ2   1850752    // 64
#define W_H1    1850880    // N*128 floats
#define W_O1    8250880    // N*128 floats
#define W_H2    1850880    // reuse H1 (dead after gather1's consumer GEMM2... H1 dead after gather1)
// zero range: W_POS .. W_SQ2+64  (pos/cnt, deg, stats) = 100,384 elements

__global__ void k_deg(const int* __restrict__ col, const float* __restrict__ w,
                      float* __restrict__ deg, int* __restrict__ cnt) {
  int e = blockIdx.x * 256 + threadIdx.x;
  if (e < NE) {
    int c = col[e];
    atomicAdd(&deg[c], w[e]);
    atomicAdd(&cnt[c], 1);
  }
}

__global__ void k_dis(float* deg_dis) {
  int i = blockIdx.x * 256 + threadIdx.x;
  if (i < NN) deg_dis[i] = rsqrtf(deg_dis[i] + 1.0f);  // +1 = self-loop weight
}

// single-block exclusive scan over (cnt[i]+1); off[] = bucket starts,
// pos[] = off+1 (slot 0 of each bucket reserved for the self-loop edge).
// cnt and pos are the SAME array (read-before-write per index, per thread).
__global__ __launch_bounds__(1024) void k_scan(int* __restrict__ cntpos, int* __restrict__ off) {
  int t = threadIdx.x;
  const int CH = (NN + 1023) / 1024;  // 49
  int lo = t * CH, hi = lo + CH;
  if (hi > NN) hi = NN;
  int s = 0;
  for (int i = lo; i < hi; ++i) s += cntpos[i] + 1;
  __shared__ int ls[1024];
  ls[t] = s;
  __syncthreads();
  for (int o = 1; o < 1024; o <<= 1) {
    int v = (t >= o) ? ls[t - o] : 0;
    __syncthreads();
    ls[t] += v;
    __syncthreads();
  }
  int base = ls[t] - s;  // exclusive prefix
  for (int i = lo; i < hi; ++i) {
    int c = cntpos[i] + 1;
    off[i] = base;
    cntpos[i] = base + 1;  // pos: first edge slot after the self edge
    base += c;
  }
  if (t == 1023) off[NN] = NN + NE;
}

__global__ void k_selfedge(const int* __restrict__ off, const float* __restrict__ dis,
                           int2* __restrict__ sedge) {
  int i = blockIdx.x * 256 + threadIdx.x;
  if (i < NN) {
    float d = dis[i];
    sedge[off[i]] = make_int2(i, __float_as_int(d * d));
  }
}

// fused: compute norm and bucket the edge by destination
__global__ void k_bucket(const int* __restrict__ adj, const float* __restrict__ w,
                         const float* __restrict__ dis, int* __restrict__ pos,
                         int2* __restrict__ sedge) {
  int e = blockIdx.x * 256 + threadIdx.x;
  if (e < NE) {
    int r = adj[e], c = adj[NE + e];
    float nm = dis[r] * w[e] * dis[c];
    int p = atomicAdd(&pos[c], 1);
    sedge[p] = make_int2(r, __float_as_int(nm));
  }
}

// GEMM1: H[N,128] = X[N,128] @ W1[128,128]
__global__ __launch_bounds__(256) void k_gemm1(const float* __restrict__ X,
                                               const float* __restrict__ W1,
                                               float* __restrict__ H) {
  __shared__ float xs[64 * 132];
  int tid = threadIdx.x;
  int row0 = blockIdx.x * 64;
  for (int i = tid; i < 64 * 32; i += 256) {
    int r = i >> 5, k4 = i & 31;
    float4 v = (row0 + r < NN) ? ((const float4*)X)[(size_t)(row0 + r) * 32 + k4]
                               : make_float4(0.f, 0.f, 0.f, 0.f);
    *(float4*)&xs[r * 132 + k4 * 4] = v;
  }
  __syncthreads();
  int cg = tid & 15, rg = tid >> 4;
  int f0 = cg * 8, r0 = rg * 4;
  float acc[4][8];
#pragma unroll
  for (int a = 0; a < 4; ++a)
#pragma unroll
    for (int b = 0; b < 8; ++b) acc[a][b] = 0.f;
  const float4* W4 = (const float4*)W1;
#pragma unroll 4
  for (int k = 0; k < 128; ++k) {
    float4 w0 = W4[k * 32 + (f0 >> 2)];
    float4 w1 = W4[k * 32 + (f0 >> 2) + 1];
    float wv[8] = {w0.x, w0.y, w0.z, w0.w, w1.x, w1.y, w1.z, w1.w};
    float xv[4];
#pragma unroll
    for (int a = 0; a < 4; ++a) xv[a] = xs[(r0 + a) * 132 + k];
#pragma unroll
    for (int a = 0; a < 4; ++a)
#pragma unroll
      for (int b = 0; b < 8; ++b) acc[a][b] += xv[a] * wv[b];
  }
#pragma unroll
  for (int a = 0; a < 4; ++a) {
    int r = row0 + r0 + a;
    if (r < NN) {
      float4* H4 = (float4*)&H[(size_t)r * 128 + f0];
      H4[0] = make_float4(acc[a][0], acc[a][1], acc[a][2], acc[a][3]);
      H4[1] = make_float4(acc[a][4], acc[a][5], acc[a][6], acc[a][7]);
    }
  }
}

// pull-gather layer1: O[c,:] = b1 + sum_{(r,nm) in bucket(c)} H[r,:]*nm
// 32 lanes x float4 per node, 8 nodes per 256-block
__global__ __launch_bounds__(256) void k_gather1(const int* __restrict__ off,
                                                 const int2* __restrict__ sedge,
                                                 const float* __restrict__ H,
                                                 const float* __restrict__ b1,
                                                 float* __restrict__ O) {
  int node = blockIdx.x * 8 + (threadIdx.x >> 5);
  int f4 = threadIdx.x & 31;
  const float4* H4 = (const float4*)H;
  float4 acc = ((const float4*)b1)[f4];
  int j0 = off[node], j1 = off[node + 1];
  for (int j = j0; j < j1; ++j) {
    int2 e = sedge[j];
    float nm = __int_as_float(e.y);
    float4 h = H4[(size_t)e.x * 32 + f4];
    acc.x = fmaf(h.x, nm, acc.x);
    acc.y = fmaf(h.y, nm, acc.y);
    acc.z = fmaf(h.z, nm, acc.z);
    acc.w = fmaf(h.w, nm, acc.w);
  }
  ((float4*)O)[(size_t)node * 32 + f4] = acc;
}

__global__ void k_stats(const float* __restrict__ X, float* __restrict__ sum,
                        float* __restrict__ sq, int C) {
  int f = threadIdx.x & (C - 1);
  int rg = threadIdx.x / C;
  int nrg = 256 / C;
  float s = 0.f, ss = 0.f;
  for (int r = blockIdx.x * nrg + rg; r < NN; r += gridDim.x * nrg) {
    float v = X[(size_t)r * C + f];
    s += v;
    ss += v * v;
  }
  __shared__ float ls[256], lss[256];
  ls[threadIdx.x] = s;
  lss[threadIdx.x] = ss;
  __syncthreads();
  if (rg == 0) {
    for (int g = 1; g < nrg; ++g) { s += ls[g * C + f]; ss += lss[g * C + f]; }
    atomicAdd(&sum[f], s);
    atomicAdd(&sq[f], ss);
  }
}

// GEMM2: H2[N,64] = leaky(BN1(O1)) @ W2[128,64]; BN+LeakyReLU fused into tile load
__global__ __launch_bounds__(256) void k_gemm2(const float* __restrict__ O1,
                                               const float* __restrict__ W2,
                                               const float* __restrict__ sum1,
                                               const float* __restrict__ sq1,
                                               const float* __restrict__ g1,
                                               const float* __restrict__ be1,
                                               float* __restrict__ H2) {
  __shared__ float xs[64 * 132];
  __shared__ float a1s[128], c1s[128];
  int tid = threadIdx.x;
  if (tid < 128) {
    float mu = sum1[tid] * (1.0f / NN);
    float var = sq1[tid] * (1.0f / NN) - mu * mu;
    float a = g1[tid] * rsqrtf(var + EPSB);
    a1s[tid] = a;
    c1s[tid] = be1[tid] - mu * a;
  }
  __syncthreads();
  int row0 = blockIdx.x * 64;
  for (int i = tid; i < 64 * 32; i += 256) {
    int r = i >> 5, k4 = i & 31;
    float4 v = (row0 + r < NN) ? ((const float4*)O1)[(size_t)(row0 + r) * 32 + k4]
                               : make_float4(0.f, 0.f, 0.f, 0.f);
    float4 a = *(const float4*)&a1s[k4 * 4];
    float4 c = *(const float4*)&c1s[k4 * 4];
    float4 y;
    y.x = fmaf(a.x, v.x, c.x);
    y.y = fmaf(a.y, v.y, c.y);
    y.z = fmaf(a.z, v.z, c.z);
    y.w = fmaf(a.w, v.w, c.w);
    y.x = y.x >= 0.f ? y.x : SLOPE * y.x;
    y.y = y.y >= 0.f ? y.y : SLOPE * y.y;
    y.z = y.z >= 0.f ? y.z : SLOPE * y.z;
    y.w = y.w >= 0.f ? y.w : SLOPE * y.w;
    *(float4*)&xs[r * 132 + k4 * 4] = y;
  }
  __syncthreads();
  int cg = tid & 7, rg = tid >> 3;
  int f0 = cg * 8, r0 = rg * 2;
  float acc[2][8];
#pragma unroll
  for (int a = 0; a < 2; ++a)
#pragma unroll
    for (int b = 0; b < 8; ++b) acc[a][b] = 0.f;
  const float4* W4 = (const float4*)W2;
#pragma unroll 4
  for (int k = 0; k < 128; ++k) {
    float4 w0 = W4[k * 16 + (f0 >> 2)];
    float4 w1 = W4[k * 16 + (f0 >> 2) + 1];
    float wv[8] = {w0.x, w0.y, w0.z, w0.w, w1.x, w1.y, w1.z, w1.w};
    float x0 = xs[(r0 + 0) * 132 + k];
    float x1 = xs[(r0 + 1) * 132 + k];
#pragma unroll
    for (int b = 0; b < 8; ++b) {
      acc[0][b] += x0 * wv[b];
      acc[1][b] += x1 * wv[b];
    }
  }
#pragma unroll
  for (int a = 0; a < 2; ++a) {
    int r = row0 + r0 + a;
    if (r < NN) {
      float4* H4 = (float4*)&H2[(size_t)r * 64 + f0];
      H4[0] = make_float4(acc[a][0], acc[a][1], acc[a][2], acc[a][3]);
      H4[1] = make_float4(acc[a][4], acc[a][5], acc[a][6], acc[a][7]);
    }
  }
}

// pull-gather layer2: 16 lanes x float4 per node, 16 nodes per 256-block
__global__ __launch_bounds__(256) void k_gather2(const int* __restrict__ off,
                                                 const int2* __restrict__ sedge,
                                                 const float* __restrict__ H,
                                                 const float* __restrict__ b2,
                                                 float* __restrict__ O) {
  int node = blockIdx.x * 16 + (threadIdx.x >> 4);
  int f4 = threadIdx.x & 15;
  const float4* H4 = (const float4*)H;
  float4 acc = ((const float4*)b2)[f4];
  int j0 = off[node], j1 = off[node + 1];
  for (int j = j0; j < j1; ++j) {
    int2 e = sedge[j];
    float nm = __int_as_float(e.y);
    float4 h = H4[(size_t)e.x * 16 + f4];
    acc.x = fmaf(h.x, nm, acc.x);
    acc.y = fmaf(h.y, nm, acc.y);
    acc.z = fmaf(h.z, nm, acc.z);
    acc.w = fmaf(h.w, nm, acc.w);
  }
  ((float4*)O)[(size_t)node * 16 + f4] = acc;
}

__global__ void k_final(float* __restrict__ O, const float* __restrict__ sum2,
                        const float* __restrict__ sq2, const float* __restrict__ g2,
                        const float* __restrict__ be2) {
  int i = blockIdx.x * 256 + threadIdx.x;
  if (i < NN * 64) {
    int f = i & 63;
    float mu = sum2[f] * (1.0f / NN);
    float var = sq2[f] * (1.0f / NN) - mu * mu;
    float a = g2[f] * rsqrtf(var + EPSB);
    float c = be2[f] - mu * a;
    O[i] = fmaf(a, O[i], c);
  }
}

extern "C" void kernel_launch(void* const* d_in, const int* in_sizes, int n_in,
                              void* d_out, int out_size, void* d_ws, size_t ws_size,
                              hipStream_t stream) {
  const int* adj = (const int*)d_in[0];
  const float* w = (const float*)d_in[1];
  const float* X = (const float*)d_in[2];
  const float* W1 = (const float*)d_in[3];
  const float* b1 = (const float*)d_in[4];
  const float* g1 = (const float*)d_in[5];
  const float* be1 = (const float*)d_in[6];
  const float* W2 = (const float*)d_in[7];
  const float* b2 = (const float*)d_in[8];
  const float* g2 = (const float*)d_in[9];
  const float* be2 = (const float*)d_in[10];
  float* ws = (float*)d_ws;
  float* out = (float*)d_out;

  int2* sedge = (int2*)(ws + W_SEDGE);
  int* off = (int*)(ws + W_OFF);
  int* pos = (int*)(ws + W_POS);   // also cnt
  float* dis = ws + W_DIS;         // also deg
  float* sum1 = ws + W_SUM1;
  float* sq1 = ws + W_SQ1;
  float* sum2 = ws + W_SUM2;
  float* sq2 = ws + W_SQ2;
  float* H1 = ws + W_H1;
  float* O1 = ws + W_O1;
  float* H2 = ws + W_H2;

  // zero cnt/pos + deg/dis + stats in one contiguous memset
  hipMemsetAsync(pos, 0, (size_t)(W_SQ2 + 64 - W_POS) * sizeof(float), stream);

  k_deg<<<(NE + 255) / 256, 256, 0, stream>>>(adj + NE, w, dis, pos);
  k_dis<<<(NN + 255) / 256, 256, 0, stream>>>(dis);
  k_scan<<<1, 1024, 0, stream>>>(pos, off);
  k_selfedge<<<(NN + 255) / 256, 256, 0, stream>>>(off, dis, sedge);
  k_bucket<<<(NE + 255) / 256, 256, 0, stream>>>(adj, w, dis, pos, sedge);

  k_gemm1<<<(NN + 63) / 64, 256, 0, stream>>>(X, W1, H1);
  k_gather1<<<NN / 8, 256, 0, stream>>>(off, sedge, H1, b1, O1);
  k_stats<<<512, 256, 0, stream>>>(O1, sum1, sq1, 128);

  k_gemm2<<<(NN + 63) / 64, 256, 0, stream>>>(O1, W2, sum1, sq1, g1, be1, H2);
  k_gather2<<<NN / 16, 256, 0, stream>>>(off, sedge, H2, b2, out);
  k_stats<<<512, 256, 0, stream>>>(out, sum2, sq2, 64);
  k_final<<<NN * 64 / 256, 256, 0, stream>>>(out, sum2, sq2, g2, be2);
}

// Round 4
// 449.992 us; speedup vs baseline: 5.1003x; 1.2087x over previous
//
#include <hip/hip_runtime.h>

#define NN 50000
#define NE 800000
#define NB 196            // ceil(NN/256)
#define EPSB 1e-5f
#define SLOPE 0.01f

// workspace layout (4-byte element offsets)
#define W_SEDGE 0          // (NE+NN) int2 = 1,700,000 slots
#define W_OFF   1700000    // NN+1 ints
#define W_PART  1750016    // 256 ints (block partials)
#define W_POS   1750432    // NN ints (aliases cnt)
#define W_DIS   1800432    // NN floats (aliases deg)
#define W_SUM1  1850432    // 128
#define W_SQ1   1850560    // 128
#define W_SUM2  1850688    // 64
#define W_SQ2   1850752    // 64
#define W_H1    1850880    // N*128 floats
#define W_O1    8250880    // N*128 floats
#define W_H2    1850880    // reuse H1 (dead after gather1)
// zero range: W_POS .. W_SQ2+64 (pos/cnt, deg, stats)

__global__ void k_deg(const int* __restrict__ col, const float* __restrict__ w,
                      float* __restrict__ deg, int* __restrict__ cnt) {
  int e = blockIdx.x * 256 + threadIdx.x;
  if (e < NE) {
    int c = col[e];
    atomicAdd(&deg[c], w[e]);
    atomicAdd(&cnt[c], 1);
  }
}

// pass A: block sums of (cnt[i]+1)
__global__ __launch_bounds__(256) void k_scanA(const int* __restrict__ cnt,
                                               int* __restrict__ part) {
  int i = blockIdx.x * 256 + threadIdx.x;
  int v = (i < NN) ? cnt[i] + 1 : 0;
  __shared__ int ls[256];
  ls[threadIdx.x] = v;
  __syncthreads();
  for (int o = 128; o > 0; o >>= 1) {
    if (threadIdx.x < o) ls[threadIdx.x] += ls[threadIdx.x + o];
    __syncthreads();
  }
  if (threadIdx.x == 0) part[blockIdx.x] = ls[0];
}

// pass B: exclusive scan of the 196 partials (single tiny block)
__global__ __launch_bounds__(256) void k_scanB(int* __restrict__ part,
                                               int* __restrict__ off) {
  int t = threadIdx.x;
  int v = (t < NB) ? part[t] : 0;
  __shared__ int ls[256];
  ls[t] = v;
  __syncthreads();
  for (int o = 1; o < 256; o <<= 1) {
    int u = (t >= o) ? ls[t - o] : 0;
    __syncthreads();
    ls[t] += u;
    __syncthreads();
  }
  if (t < NB) part[t] = ls[t] - v;  // exclusive
  if (t == 0) off[NN] = NN + NE;
}

// pass C: block-local exclusive scan + global base; fuses dis=rsqrt(deg+1)
// and the self-loop edge write (slot 0 of each bucket).
__global__ __launch_bounds__(256) void k_scanC(int* __restrict__ cntpos,
                                               const int* __restrict__ part,
                                               float* __restrict__ degdis,
                                               int* __restrict__ off,
                                               int2* __restrict__ sedge) {
  int i = blockIdx.x * 256 + threadIdx.x;
  int t = threadIdx.x;
  int v = (i < NN) ? cntpos[i] + 1 : 0;
  __shared__ int ls[256];
  ls[t] = v;
  __syncthreads();
  for (int o = 1; o < 256; o <<= 1) {
    int u = (t >= o) ? ls[t - o] : 0;
    __syncthreads();
    ls[t] += u;
    __syncthreads();
  }
  if (i < NN) {
    int base = part[blockIdx.x] + ls[t] - v;  // exclusive global prefix
    off[i] = base;
    cntpos[i] = base + 1;                     // first slot after self edge
    float d = rsqrtf(degdis[i] + 1.0f);
    degdis[i] = d;
    sedge[base] = make_int2(i, __float_as_int(d * d));
  }
}

// fused: compute norm and bucket the edge by destination
__global__ void k_bucket(const int* __restrict__ adj, const float* __restrict__ w,
                         const float* __restrict__ dis, int* __restrict__ pos,
                         int2* __restrict__ sedge) {
  int e = blockIdx.x * 256 + threadIdx.x;
  if (e < NE) {
    int r = adj[e], c = adj[NE + e];
    float nm = dis[r] * w[e] * dis[c];
    int p = atomicAdd(&pos[c], 1);
    sedge[p] = make_int2(r, __float_as_int(nm));
  }
}

// GEMM1: H[N,128] = X[N,128] @ W1[128,128]
__global__ __launch_bounds__(256) void k_gemm1(const float* __restrict__ X,
                                               const float* __restrict__ W1,
                                               float* __restrict__ H) {
  __shared__ float xs[64 * 132];
  int tid = threadIdx.x;
  int row0 = blockIdx.x * 64;
  for (int i = tid; i < 64 * 32; i += 256) {
    int r = i >> 5, k4 = i & 31;
    float4 v = (row0 + r < NN) ? ((const float4*)X)[(size_t)(row0 + r) * 32 + k4]
                               : make_float4(0.f, 0.f, 0.f, 0.f);
    *(float4*)&xs[r * 132 + k4 * 4] = v;
  }
  __syncthreads();
  int cg = tid & 15, rg = tid >> 4;
  int f0 = cg * 8, r0 = rg * 4;
  float acc[4][8];
#pragma unroll
  for (int a = 0; a < 4; ++a)
#pragma unroll
    for (int b = 0; b < 8; ++b) acc[a][b] = 0.f;
  const float4* W4 = (const float4*)W1;
#pragma unroll 4
  for (int k = 0; k < 128; ++k) {
    float4 w0 = W4[k * 32 + (f0 >> 2)];
    float4 w1 = W4[k * 32 + (f0 >> 2) + 1];
    float wv[8] = {w0.x, w0.y, w0.z, w0.w, w1.x, w1.y, w1.z, w1.w};
    float xv[4];
#pragma unroll
    for (int a = 0; a < 4; ++a) xv[a] = xs[(r0 + a) * 132 + k];
#pragma unroll
    for (int a = 0; a < 4; ++a)
#pragma unroll
      for (int b = 0; b < 8; ++b) acc[a][b] += xv[a] * wv[b];
  }
#pragma unroll
  for (int a = 0; a < 4; ++a) {
    int r = row0 + r0 + a;
    if (r < NN) {
      float4* H4 = (float4*)&H[(size_t)r * 128 + f0];
      H4[0] = make_float4(acc[a][0], acc[a][1], acc[a][2], acc[a][3]);
      H4[1] = make_float4(acc[a][4], acc[a][5], acc[a][6], acc[a][7]);
    }
  }
}

// pull-gather layer1: O[c,:] = b1 + sum_{(r,nm) in bucket(c)} H[r,:]*nm
__global__ __launch_bounds__(256) void k_gather1(const int* __restrict__ off,
                                                 const int2* __restrict__ sedge,
                                                 const float* __restrict__ H,
                                                 const float* __restrict__ b1,
                                                 float* __restrict__ O) {
  int node = blockIdx.x * 8 + (threadIdx.x >> 5);
  int f4 = threadIdx.x & 31;
  const float4* H4 = (const float4*)H;
  float4 acc = ((const float4*)b1)[f4];
  int j0 = off[node], j1 = off[node + 1];
  for (int j = j0; j < j1; ++j) {
    int2 e = sedge[j];
    float nm = __int_as_float(e.y);
    float4 h = H4[(size_t)e.x * 32 + f4];
    acc.x = fmaf(h.x, nm, acc.x);
    acc.y = fmaf(h.y, nm, acc.y);
    acc.z = fmaf(h.z, nm, acc.z);
    acc.w = fmaf(h.w, nm, acc.w);
  }
  ((float4*)O)[(size_t)node * 32 + f4] = acc;
}

__global__ void k_stats(const float* __restrict__ X, float* __restrict__ sum,
                        float* __restrict__ sq, int C) {
  int f = threadIdx.x & (C - 1);
  int rg = threadIdx.x / C;
  int nrg = 256 / C;
  float s = 0.f, ss = 0.f;
  for (int r = blockIdx.x * nrg + rg; r < NN; r += gridDim.x * nrg) {
    float v = X[(size_t)r * C + f];
    s += v;
    ss += v * v;
  }
  __shared__ float ls[256], lss[256];
  ls[threadIdx.x] = s;
  lss[threadIdx.x] = ss;
  __syncthreads();
  if (rg == 0) {
    for (int g = 1; g < nrg; ++g) { s += ls[g * C + f]; ss += lss[g * C + f]; }
    atomicAdd(&sum[f], s);
    atomicAdd(&sq[f], ss);
  }
}

// GEMM2: H2[N,64] = leaky(BN1(O1)) @ W2[128,64]; BN+LeakyReLU fused into tile load
__global__ __launch_bounds__(256) void k_gemm2(const float* __restrict__ O1,
                                               const float* __restrict__ W2,
                                               const float* __restrict__ sum1,
                                               const float* __restrict__ sq1,
                                               const float* __restrict__ g1,
                                               const float* __restrict__ be1,
                                               float* __restrict__ H2) {
  __shared__ float xs[64 * 132];
  __shared__ float a1s[128], c1s[128];
  int tid = threadIdx.x;
  if (tid < 128) {
    float mu = sum1[tid] * (1.0f / NN);
    float var = sq1[tid] * (1.0f / NN) - mu * mu;
    float a = g1[tid] * rsqrtf(var + EPSB);
    a1s[tid] = a;
    c1s[tid] = be1[tid] - mu * a;
  }
  __syncthreads();
  int row0 = blockIdx.x * 64;
  for (int i = tid; i < 64 * 32; i += 256) {
    int r = i >> 5, k4 = i & 31;
    float4 v = (row0 + r < NN) ? ((const float4*)O1)[(size_t)(row0 + r) * 32 + k4]
                               : make_float4(0.f, 0.f, 0.f, 0.f);
    float4 a = *(const float4*)&a1s[k4 * 4];
    float4 c = *(const float4*)&c1s[k4 * 4];
    float4 y;
    y.x = fmaf(a.x, v.x, c.x);
    y.y = fmaf(a.y, v.y, c.y);
    y.z = fmaf(a.z, v.z, c.z);
    y.w = fmaf(a.w, v.w, c.w);
    y.x = y.x >= 0.f ? y.x : SLOPE * y.x;
    y.y = y.y >= 0.f ? y.y : SLOPE * y.y;
    y.z = y.z >= 0.f ? y.z : SLOPE * y.z;
    y.w = y.w >= 0.f ? y.w : SLOPE * y.w;
    *(float4*)&xs[r * 132 + k4 * 4] = y;
  }
  __syncthreads();
  int cg = tid & 7, rg = tid >> 3;
  int f0 = cg * 8, r0 = rg * 2;
  float acc[2][8];
#pragma unroll
  for (int a = 0; a < 2; ++a)
#pragma unroll
    for (int b = 0; b < 8; ++b) acc[a][b] = 0.f;
  const float4* W4 = (const float4*)W2;
#pragma unroll 4
  for (int k = 0; k < 128; ++k) {
    float4 w0 = W4[k * 16 + (f0 >> 2)];
    float4 w1 = W4[k * 16 + (f0 >> 2) + 1];
    float wv[8] = {w0.x, w0.y, w0.z, w0.w, w1.x, w1.y, w1.z, w1.w};
    float x0 = xs[(r0 + 0) * 132 + k];
    float x1 = xs[(r0 + 1) * 132 + k];
#pragma unroll
    for (int b = 0; b < 8; ++b) {
      acc[0][b] += x0 * wv[b];
      acc[1][b] += x1 * wv[b];
    }
  }
#pragma unroll
  for (int a = 0; a < 2; ++a) {
    int r = row0 + r0 + a;
    if (r < NN) {
      float4* H4 = (float4*)&H2[(size_t)r * 64 + f0];
      H4[0] = make_float4(acc[a][0], acc[a][1], acc[a][2], acc[a][3]);
      H4[1] = make_float4(acc[a][4], acc[a][5], acc[a][6], acc[a][7]);
    }
  }
}

// pull-gather layer2: 16 lanes x float4 per node
__global__ __launch_bounds__(256) void k_gather2(const int* __restrict__ off,
                                                 const int2* __restrict__ sedge,
                                                 const float* __restrict__ H,
                                                 const float* __restrict__ b2,
                                                 float* __restrict__ O) {
  int node = blockIdx.x * 16 + (threadIdx.x >> 4);
  int f4 = threadIdx.x & 15;
  const float4* H4 = (const float4*)H;
  float4 acc = ((const float4*)b2)[f4];
  int j0 = off[node], j1 = off[node + 1];
  for (int j = j0; j < j1; ++j) {
    int2 e = sedge[j];
    float nm = __int_as_float(e.y);
    float4 h = H4[(size_t)e.x * 16 + f4];
    acc.x = fmaf(h.x, nm, acc.x);
    acc.y = fmaf(h.y, nm, acc.y);
    acc.z = fmaf(h.z, nm, acc.z);
    acc.w = fmaf(h.w, nm, acc.w);
  }
  ((float4*)O)[(size_t)node * 16 + f4] = acc;
}

__global__ void k_final(float* __restrict__ O, const float* __restrict__ sum2,
                        const float* __restrict__ sq2, const float* __restrict__ g2,
                        const float* __restrict__ be2) {
  int i = blockIdx.x * 256 + threadIdx.x;
  if (i < NN * 64) {
    int f = i & 63;
    float mu = sum2[f] * (1.0f / NN);
    float var = sq2[f] * (1.0f / NN) - mu * mu;
    float a = g2[f] * rsqrtf(var + EPSB);
    float c = be2[f] - mu * a;
    O[i] = fmaf(a, O[i], c);
  }
}

extern "C" void kernel_launch(void* const* d_in, const int* in_sizes, int n_in,
                              void* d_out, int out_size, void* d_ws, size_t ws_size,
                              hipStream_t stream) {
  const int* adj = (const int*)d_in[0];
  const float* w = (const float*)d_in[1];
  const float* X = (const float*)d_in[2];
  const float* W1 = (const float*)d_in[3];
  const float* b1 = (const float*)d_in[4];
  const float* g1 = (const float*)d_in[5];
  const float* be1 = (const float*)d_in[6];
  const float* W2 = (const float*)d_in[7];
  const float* b2 = (const float*)d_in[8];
  const float* g2 = (const float*)d_in[9];
  const float* be2 = (const float*)d_in[10];
  float* ws = (float*)d_ws;
  float* out = (float*)d_out;

  int2* sedge = (int2*)(ws + W_SEDGE);
  int* off = (int*)(ws + W_OFF);
  int* part = (int*)(ws + W_PART);
  int* pos = (int*)(ws + W_POS);   // also cnt
  float* dis = ws + W_DIS;         // also deg
  float* sum1 = ws + W_SUM1;
  float* sq1 = ws + W_SQ1;
  float* sum2 = ws + W_SUM2;
  float* sq2 = ws + W_SQ2;
  float* H1 = ws + W_H1;
  float* O1 = ws + W_O1;
  float* H2 = ws + W_H2;

  // zero cnt/pos + deg/dis + stats in one contiguous memset
  hipMemsetAsync(pos, 0, (size_t)(W_SQ2 + 64 - W_POS) * sizeof(float), stream);

  k_deg<<<(NE + 255) / 256, 256, 0, stream>>>(adj + NE, w, dis, pos);
  k_scanA<<<NB, 256, 0, stream>>>(pos, part);
  k_scanB<<<1, 256, 0, stream>>>(part, off);
  k_scanC<<<NB, 256, 0, stream>>>(pos, part, dis, off, sedge);
  k_bucket<<<(NE + 255) / 256, 256, 0, stream>>>(adj, w, dis, pos, sedge);

  k_gemm1<<<(NN + 63) / 64, 256, 0, stream>>>(X, W1, H1);
  k_gather1<<<NN / 8, 256, 0, stream>>>(off, sedge, H1, b1, O1);
  k_stats<<<512, 256, 0, stream>>>(O1, sum1, sq1, 128);

  k_gemm2<<<(NN + 63) / 64, 256, 0, stream>>>(O1, W2, sum1, sq1, g1, be1, H2);
  k_gather2<<<NN / 16, 256, 0, stream>>>(off, sedge, H2, b2, out);
  k_stats<<<512, 256, 0, stream>>>(out, sum2, sq2, 64);
  k_final<<<NN * 64 / 256, 256, 0, stream>>>(out, sum2, sq2, g2, be2);
}

// Round 5
// 396.471 us; speedup vs baseline: 5.7889x; 1.1350x over previous
//
#include <hip/hip_runtime.h>

#define NN 50000
#define NE 800000
#define NB 196            // ceil(NN/256)
#define EPSB 1e-5f
#define SLOPE 0.01f
#define FPS 67108864.0f   // 2^26 fixed-point scale for degree sum

// workspace layout (4-byte element offsets)
#define W_SEDGE 0          // (NE+NN) int2 = 1,700,000 ints
#define W_OFF   1700000    // NN+1 ints
#define W_PART  1750016    // 256 ints (block partials)
#define W_POS   1750432    // NN ints
#define W_DIS   1800432    // NN floats
#define W_SUM1  1850432    // 128
#define W_SQ1   1850560    // 128
#define W_SUM2  1850688    // 64
#define W_SQ2   1850752    // 64
#define W_H1    1850880    // N*128 floats
#define W_O1    8250880    // N*128 floats
#define W_PACK  8250880    // NN u64 — aliases O1 (dead before gather1 writes O1)
#define W_H2    1850880    // reuse H1 (dead after gather1)

// one packed u64 atomic per edge: [63:16] = sum(w)*2^26, [15:0] = count
__global__ void k_deg(const int* __restrict__ col, const float* __restrict__ w,
                      unsigned long long* __restrict__ pack) {
  int e = blockIdx.x * 256 + threadIdx.x;
  if (e < NE) {
    int c = col[e];
    unsigned long long v =
        (((unsigned long long)__float2uint_rn(w[e] * FPS)) << 16) | 1ull;
    atomicAdd(&pack[c], v);
  }
}

// pass A: block sums of (cnt[i]+1)
__global__ __launch_bounds__(256) void k_scanA(const unsigned long long* __restrict__ pack,
                                               int* __restrict__ part) {
  int i = blockIdx.x * 256 + threadIdx.x;
  int v = (i < NN) ? (int)(pack[i] & 0xFFFFull) + 1 : 0;
  __shared__ int ls[256];
  ls[threadIdx.x] = v;
  __syncthreads();
  for (int o = 128; o > 0; o >>= 1) {
    if (threadIdx.x < o) ls[threadIdx.x] += ls[threadIdx.x + o];
    __syncthreads();
  }
  if (threadIdx.x == 0) part[blockIdx.x] = ls[0];
}

// pass B: exclusive scan of the 196 partials (single tiny block)
__global__ __launch_bounds__(256) void k_scanB(int* __restrict__ part,
                                               int* __restrict__ off) {
  int t = threadIdx.x;
  int v = (t < NB) ? part[t] : 0;
  __shared__ int ls[256];
  ls[t] = v;
  __syncthreads();
  for (int o = 1; o < 256; o <<= 1) {
    int u = (t >= o) ? ls[t - o] : 0;
    __syncthreads();
    ls[t] += u;
    __syncthreads();
  }
  if (t < NB) part[t] = ls[t] - v;  // exclusive
  if (t == 0) off[NN] = NN + NE;
}

// pass C: block-local exclusive scan + global base; unpacks deg, computes dis,
// writes off/pos and the self-loop edge (slot 0 of each bucket).
__global__ __launch_bounds__(256) void k_scanC(const unsigned long long* __restrict__ pack,
                                               const int* __restrict__ part,
                                               int* __restrict__ pos,
                                               float* __restrict__ dis,
                                               int* __restrict__ off,
                                               int2* __restrict__ sedge) {
  int i = blockIdx.x * 256 + threadIdx.x;
  int t = threadIdx.x;
  unsigned long long p = (i < NN) ? pack[i] : 0ull;
  int v = (i < NN) ? (int)(p & 0xFFFFull) + 1 : 0;
  __shared__ int ls[256];
  ls[t] = v;
  __syncthreads();
  for (int o = 1; o < 256; o <<= 1) {
    int u = (t >= o) ? ls[t - o] : 0;
    __syncthreads();
    ls[t] += u;
    __syncthreads();
  }
  if (i < NN) {
    int base = part[blockIdx.x] + ls[t] - v;  // exclusive global prefix
    off[i] = base;
    pos[i] = base + 1;                        // first slot after self edge
    float deg = (float)(p >> 16) * (1.0f / FPS);
    float d = rsqrtf(deg + 1.0f);
    dis[i] = d;
    sedge[base] = make_int2(i, __float_as_int(d * d));
  }
}

// fused: compute norm and bucket the edge by destination
__global__ void k_bucket(const int* __restrict__ adj, const float* __restrict__ w,
                         const float* __restrict__ dis, int* __restrict__ pos,
                         int2* __restrict__ sedge) {
  int e = blockIdx.x * 256 + threadIdx.x;
  if (e < NE) {
    int r = adj[e], c = adj[NE + e];
    float nm = dis[r] * w[e] * dis[c];
    int p = atomicAdd(&pos[c], 1);
    sedge[p] = make_int2(r, __float_as_int(nm));
  }
}

// GEMM1: H[N,128] = X[N,128] @ W1[128,128]
__global__ __launch_bounds__(256) void k_gemm1(const float* __restrict__ X,
                                               const float* __restrict__ W1,
                                               float* __restrict__ H) {
  __shared__ float xs[64 * 132];
  int tid = threadIdx.x;
  int row0 = blockIdx.x * 64;
  for (int i = tid; i < 64 * 32; i += 256) {
    int r = i >> 5, k4 = i & 31;
    float4 v = (row0 + r < NN) ? ((const float4*)X)[(size_t)(row0 + r) * 32 + k4]
                               : make_float4(0.f, 0.f, 0.f, 0.f);
    *(float4*)&xs[r * 132 + k4 * 4] = v;
  }
  __syncthreads();
  int cg = tid & 15, rg = tid >> 4;
  int f0 = cg * 8, r0 = rg * 4;
  float acc[4][8];
#pragma unroll
  for (int a = 0; a < 4; ++a)
#pragma unroll
    for (int b = 0; b < 8; ++b) acc[a][b] = 0.f;
  const float4* W4 = (const float4*)W1;
#pragma unroll 4
  for (int k = 0; k < 128; ++k) {
    float4 w0 = W4[k * 32 + (f0 >> 2)];
    float4 w1 = W4[k * 32 + (f0 >> 2) + 1];
    float wv[8] = {w0.x, w0.y, w0.z, w0.w, w1.x, w1.y, w1.z, w1.w};
    float xv[4];
#pragma unroll
    for (int a = 0; a < 4; ++a) xv[a] = xs[(r0 + a) * 132 + k];
#pragma unroll
    for (int a = 0; a < 4; ++a)
#pragma unroll
      for (int b = 0; b < 8; ++b) acc[a][b] += xv[a] * wv[b];
  }
#pragma unroll
  for (int a = 0; a < 4; ++a) {
    int r = row0 + r0 + a;
    if (r < NN) {
      float4* H4 = (float4*)&H[(size_t)r * 128 + f0];
      H4[0] = make_float4(acc[a][0], acc[a][1], acc[a][2], acc[a][3]);
      H4[1] = make_float4(acc[a][4], acc[a][5], acc[a][6], acc[a][7]);
    }
  }
}

// pull-gather layer1: O[c,:] = b1 + sum_{(r,nm) in bucket(c)} H[r,:]*nm
// unrolled x2 so both edge loads issue before their FMAs
__global__ __launch_bounds__(256) void k_gather1(const int* __restrict__ off,
                                                 const int2* __restrict__ sedge,
                                                 const float* __restrict__ H,
                                                 const float* __restrict__ b1,
                                                 float* __restrict__ O) {
  int node = blockIdx.x * 8 + (threadIdx.x >> 5);
  int f4 = threadIdx.x & 31;
  const float4* H4 = (const float4*)H;
  float4 acc = ((const float4*)b1)[f4];
  int j0 = off[node], j1 = off[node + 1];
  int j = j0;
  for (; j + 1 < j1; j += 2) {
    int2 e0 = sedge[j];
    int2 e1 = sedge[j + 1];
    float4 h0 = H4[(size_t)e0.x * 32 + f4];
    float4 h1 = H4[(size_t)e1.x * 32 + f4];
    float n0 = __int_as_float(e0.y), n1 = __int_as_float(e1.y);
    acc.x = fmaf(h0.x, n0, acc.x);
    acc.y = fmaf(h0.y, n0, acc.y);
    acc.z = fmaf(h0.z, n0, acc.z);
    acc.w = fmaf(h0.w, n0, acc.w);
    acc.x = fmaf(h1.x, n1, acc.x);
    acc.y = fmaf(h1.y, n1, acc.y);
    acc.z = fmaf(h1.z, n1, acc.z);
    acc.w = fmaf(h1.w, n1, acc.w);
  }
  if (j < j1) {
    int2 e = sedge[j];
    float nm = __int_as_float(e.y);
    float4 h = H4[(size_t)e.x * 32 + f4];
    acc.x = fmaf(h.x, nm, acc.x);
    acc.y = fmaf(h.y, nm, acc.y);
    acc.z = fmaf(h.z, nm, acc.z);
    acc.w = fmaf(h.w, nm, acc.w);
  }
  ((float4*)O)[(size_t)node * 32 + f4] = acc;
}

__global__ void k_stats(const float* __restrict__ X, float* __restrict__ sum,
                        float* __restrict__ sq, int C) {
  int f = threadIdx.x & (C - 1);
  int rg = threadIdx.x / C;
  int nrg = 256 / C;
  float s = 0.f, ss = 0.f;
  for (int r = blockIdx.x * nrg + rg; r < NN; r += gridDim.x * nrg) {
    float v = X[(size_t)r * C + f];
    s += v;
    ss += v * v;
  }
  __shared__ float ls[256], lss[256];
  ls[threadIdx.x] = s;
  lss[threadIdx.x] = ss;
  __syncthreads();
  if (rg == 0) {
    for (int g = 1; g < nrg; ++g) { s += ls[g * C + f]; ss += lss[g * C + f]; }
    atomicAdd(&sum[f], s);
    atomicAdd(&sq[f], ss);
  }
}

// GEMM2: H2[N,64] = leaky(BN1(O1)) @ W2[128,64]; BN+LeakyReLU fused into tile load
__global__ __launch_bounds__(256) void k_gemm2(const float* __restrict__ O1,
                                               const float* __restrict__ W2,
                                               const float* __restrict__ sum1,
                                               const float* __restrict__ sq1,
                                               const float* __restrict__ g1,
                                               const float* __restrict__ be1,
                                               float* __restrict__ H2) {
  __shared__ float xs[64 * 132];
  __shared__ float a1s[128], c1s[128];
  int tid = threadIdx.x;
  if (tid < 128) {
    float mu = sum1[tid] * (1.0f / NN);
    float var = sq1[tid] * (1.0f / NN) - mu * mu;
    float a = g1[tid] * rsqrtf(var + EPSB);
    a1s[tid] = a;
    c1s[tid] = be1[tid] - mu * a;
  }
  __syncthreads();
  int row0 = blockIdx.x * 64;
  for (int i = tid; i < 64 * 32; i += 256) {
    int r = i >> 5, k4 = i & 31;
    float4 v = (row0 + r < NN) ? ((const float4*)O1)[(size_t)(row0 + r) * 32 + k4]
                               : make_float4(0.f, 0.f, 0.f, 0.f);
    float4 a = *(const float4*)&a1s[k4 * 4];
    float4 c = *(const float4*)&c1s[k4 * 4];
    float4 y;
    y.x = fmaf(a.x, v.x, c.x);
    y.y = fmaf(a.y, v.y, c.y);
    y.z = fmaf(a.z, v.z, c.z);
    y.w = fmaf(a.w, v.w, c.w);
    y.x = y.x >= 0.f ? y.x : SLOPE * y.x;
    y.y = y.y >= 0.f ? y.y : SLOPE * y.y;
    y.z = y.z >= 0.f ? y.z : SLOPE * y.z;
    y.w = y.w >= 0.f ? y.w : SLOPE * y.w;
    *(float4*)&xs[r * 132 + k4 * 4] = y;
  }
  __syncthreads();
  int cg = tid & 7, rg = tid >> 3;
  int f0 = cg * 8, r0 = rg * 2;
  float acc[2][8];
#pragma unroll
  for (int a = 0; a < 2; ++a)
#pragma unroll
    for (int b = 0; b < 8; ++b) acc[a][b] = 0.f;
  const float4* W4 = (const float4*)W2;
#pragma unroll 4
  for (int k = 0; k < 128; ++k) {
    float4 w0 = W4[k * 16 + (f0 >> 2)];
    float4 w1 = W4[k * 16 + (f0 >> 2) + 1];
    float wv[8] = {w0.x, w0.y, w0.z, w0.w, w1.x, w1.y, w1.z, w1.w};
    float x0 = xs[(r0 + 0) * 132 + k];
    float x1 = xs[(r0 + 1) * 132 + k];
#pragma unroll
    for (int b = 0; b < 8; ++b) {
      acc[0][b] += x0 * wv[b];
      acc[1][b] += x1 * wv[b];
    }
  }
#pragma unroll
  for (int a = 0; a < 2; ++a) {
    int r = row0 + r0 + a;
    if (r < NN) {
      float4* H4 = (float4*)&H2[(size_t)r * 64 + f0];
      H4[0] = make_float4(acc[a][0], acc[a][1], acc[a][2], acc[a][3]);
      H4[1] = make_float4(acc[a][4], acc[a][5], acc[a][6], acc[a][7]);
    }
  }
}

// pull-gather layer2: 16 lanes x float4 per node, unrolled x2
__global__ __launch_bounds__(256) void k_gather2(const int* __restrict__ off,
                                                 const int2* __restrict__ sedge,
                                                 const float* __restrict__ H,
                                                 const float* __restrict__ b2,
                                                 float* __restrict__ O) {
  int node = blockIdx.x * 16 + (threadIdx.x >> 4);
  int f4 = threadIdx.x & 15;
  const float4* H4 = (const float4*)H;
  float4 acc = ((const float4*)b2)[f4];
  int j0 = off[node], j1 = off[node + 1];
  int j = j0;
  for (; j + 1 < j1; j += 2) {
    int2 e0 = sedge[j];
    int2 e1 = sedge[j + 1];
    float4 h0 = H4[(size_t)e0.x * 16 + f4];
    float4 h1 = H4[(size_t)e1.x * 16 + f4];
    float n0 = __int_as_float(e0.y), n1 = __int_as_float(e1.y);
    acc.x = fmaf(h0.x, n0, acc.x);
    acc.y = fmaf(h0.y, n0, acc.y);
    acc.z = fmaf(h0.z, n0, acc.z);
    acc.w = fmaf(h0.w, n0, acc.w);
    acc.x = fmaf(h1.x, n1, acc.x);
    acc.y = fmaf(h1.y, n1, acc.y);
    acc.z = fmaf(h1.z, n1, acc.z);
    acc.w = fmaf(h1.w, n1, acc.w);
  }
  if (j < j1) {
    int2 e = sedge[j];
    float nm = __int_as_float(e.y);
    float4 h = H4[(size_t)e.x * 16 + f4];
    acc.x = fmaf(h.x, nm, acc.x);
    acc.y = fmaf(h.y, nm, acc.y);
    acc.z = fmaf(h.z, nm, acc.z);
    acc.w = fmaf(h.w, nm, acc.w);
  }
  ((float4*)O)[(size_t)node * 16 + f4] = acc;
}

__global__ void k_final(float* __restrict__ O, const float* __restrict__ sum2,
                        const float* __restrict__ sq2, const float* __restrict__ g2,
                        const float* __restrict__ be2) {
  int i = blockIdx.x * 256 + threadIdx.x;
  if (i < NN * 64) {
    int f = i & 63;
    float mu = sum2[f] * (1.0f / NN);
    float var = sq2[f] * (1.0f / NN) - mu * mu;
    float a = g2[f] * rsqrtf(var + EPSB);
    float c = be2[f] - mu * a;
    O[i] = fmaf(a, O[i], c);
  }
}

extern "C" void kernel_launch(void* const* d_in, const int* in_sizes, int n_in,
                              void* d_out, int out_size, void* d_ws, size_t ws_size,
                              hipStream_t stream) {
  const int* adj = (const int*)d_in[0];
  const float* w = (const float*)d_in[1];
  const float* X = (const float*)d_in[2];
  const float* W1 = (const float*)d_in[3];
  const float* b1 = (const float*)d_in[4];
  const float* g1 = (const float*)d_in[5];
  const float* be1 = (const float*)d_in[6];
  const float* W2 = (const float*)d_in[7];
  const float* b2 = (const float*)d_in[8];
  const float* g2 = (const float*)d_in[9];
  const float* be2 = (const float*)d_in[10];
  float* ws = (float*)d_ws;
  float* out = (float*)d_out;

  int2* sedge = (int2*)(ws + W_SEDGE);
  int* off = (int*)(ws + W_OFF);
  int* part = (int*)(ws + W_PART);
  int* pos = (int*)(ws + W_POS);
  float* dis = ws + W_DIS;
  float* sum1 = ws + W_SUM1;
  float* sq1 = ws + W_SQ1;
  float* sum2 = ws + W_SUM2;
  float* sq2 = ws + W_SQ2;
  float* H1 = ws + W_H1;
  float* O1 = ws + W_O1;
  float* H2 = ws + W_H2;
  unsigned long long* pack = (unsigned long long*)(ws + W_PACK);

  // zero the pack array (aliases O1, re-zeroed every call) + BN stats
  hipMemsetAsync(pack, 0, (size_t)NN * 8, stream);
  hipMemsetAsync(sum1, 0, (size_t)(W_SQ2 + 64 - W_SUM1) * sizeof(float), stream);

  k_deg<<<(NE + 255) / 256, 256, 0, stream>>>(adj + NE, w, pack);
  k_scanA<<<NB, 256, 0, stream>>>(pack, part);
  k_scanB<<<1, 256, 0, stream>>>(part, off);
  k_scanC<<<NB, 256, 0, stream>>>(pack, part, pos, dis, off, sedge);
  k_bucket<<<(NE + 255) / 256, 256, 0, stream>>>(adj, w, dis, pos, sedge);

  k_gemm1<<<(NN + 63) / 64, 256, 0, stream>>>(X, W1, H1);
  k_gather1<<<NN / 8, 256, 0, stream>>>(off, sedge, H1, b1, O1);
  k_stats<<<512, 256, 0, stream>>>(O1, sum1, sq1, 128);

  k_gemm2<<<(NN + 63) / 64, 256, 0, stream>>>(O1, W2, sum1, sq1, g1, be1, H2);
  k_gather2<<<NN / 16, 256, 0, stream>>>(off, sedge, H2, b2, out);
  k_stats<<<512, 256, 0, stream>>>(out, sum2, sq2, 64);
  k_final<<<NN * 64 / 256, 256, 0, stream>>>(out, sum2, sq2, g2, be2);
}

// Round 6
// 370.079 us; speedup vs baseline: 6.2017x; 1.0713x over previous
//
#include <hip/hip_runtime.h>
#include <hip/hip_fp16.h>

#define NN 50000
#define NE 800000
#define NB 196            // ceil(NN/256)
#define EPSB 1e-5f
#define SLOPE 0.01f
#define FPS 67108864.0f   // 2^26 fixed-point scale for degree sum

// workspace layout (4-byte element offsets)
#define W_SEDGE 0          // (NE+NN) int2 = 1,700,000 ints
#define W_OFF   1700000    // NN+1 ints
#define W_PART  1750016    // 256 ints (block partials)
#define W_POS   1750432    // NN ints
#define W_DIS   1800432    // NN floats
#define W_SUM1  1850432    // 128
#define W_SQ1   1850560    // 128
#define W_SUM2  1850688    // 64
#define W_SQ2   1850752    // 64
#define W_H1    1850880    // N*128 halves (= N*64 float slots); H2 fp16 aliases
#define W_O1    8250880    // N*128 floats
#define W_PACK  8250880    // NN u64 — aliases O1 (dead before gather1 writes O1)

union H8 { uint4 u; __half2 h[4]; };

// one packed u64 atomic per edge: [63:16] = sum(w)*2^26, [15:0] = count
__global__ void k_deg(const int* __restrict__ col, const float* __restrict__ w,
                      unsigned long long* __restrict__ pack) {
  int e = blockIdx.x * 256 + threadIdx.x;
  if (e < NE) {
    int c = col[e];
    unsigned long long v =
        (((unsigned long long)__float2uint_rn(w[e] * FPS)) << 16) | 1ull;
    atomicAdd(&pack[c], v);
  }
}

// pass A: block sums of (cnt[i]+1)
__global__ __launch_bounds__(256) void k_scanA(const unsigned long long* __restrict__ pack,
                                               int* __restrict__ part) {
  int i = blockIdx.x * 256 + threadIdx.x;
  int v = (i < NN) ? (int)(pack[i] & 0xFFFFull) + 1 : 0;
  __shared__ int ls[256];
  ls[threadIdx.x] = v;
  __syncthreads();
  for (int o = 128; o > 0; o >>= 1) {
    if (threadIdx.x < o) ls[threadIdx.x] += ls[threadIdx.x + o];
    __syncthreads();
  }
  if (threadIdx.x == 0) part[blockIdx.x] = ls[0];
}

// pass B: exclusive scan of the 196 partials (single tiny block)
__global__ __launch_bounds__(256) void k_scanB(int* __restrict__ part,
                                               int* __restrict__ off) {
  int t = threadIdx.x;
  int v = (t < NB) ? part[t] : 0;
  __shared__ int ls[256];
  ls[t] = v;
  __syncthreads();
  for (int o = 1; o < 256; o <<= 1) {
    int u = (t >= o) ? ls[t - o] : 0;
    __syncthreads();
    ls[t] += u;
    __syncthreads();
  }
  if (t < NB) part[t] = ls[t] - v;  // exclusive
  if (t == 0) off[NN] = NN + NE;
}

// pass C: block-local exclusive scan + global base; unpacks deg, computes dis,
// writes off/pos and the self-loop edge (slot 0 of each bucket).
__global__ __launch_bounds__(256) void k_scanC(const unsigned long long* __restrict__ pack,
                                               const int* __restrict__ part,
                                               int* __restrict__ pos,
                                               float* __restrict__ dis,
                                               int* __restrict__ off,
                                               int2* __restrict__ sedge) {
  int i = blockIdx.x * 256 + threadIdx.x;
  int t = threadIdx.x;
  unsigned long long p = (i < NN) ? pack[i] : 0ull;
  int v = (i < NN) ? (int)(p & 0xFFFFull) + 1 : 0;
  __shared__ int ls[256];
  ls[t] = v;
  __syncthreads();
  for (int o = 1; o < 256; o <<= 1) {
    int u = (t >= o) ? ls[t - o] : 0;
    __syncthreads();
    ls[t] += u;
    __syncthreads();
  }
  if (i < NN) {
    int base = part[blockIdx.x] + ls[t] - v;  // exclusive global prefix
    off[i] = base;
    pos[i] = base + 1;                        // first slot after self edge
    float deg = (float)(p >> 16) * (1.0f / FPS);
    float d = rsqrtf(deg + 1.0f);
    dis[i] = d;
    sedge[base] = make_int2(i, __float_as_int(d * d));
  }
}

// fused: compute norm and bucket the edge by destination
__global__ void k_bucket(const int* __restrict__ adj, const float* __restrict__ w,
                         const float* __restrict__ dis, int* __restrict__ pos,
                         int2* __restrict__ sedge) {
  int e = blockIdx.x * 256 + threadIdx.x;
  if (e < NE) {
    int r = adj[e], c = adj[NE + e];
    float nm = dis[r] * w[e] * dis[c];
    int p = atomicAdd(&pos[c], 1);
    sedge[p] = make_int2(r, __float_as_int(nm));
  }
}

// GEMM1: H[N,128](fp16) = X[N,128] @ W1[128,128]
__global__ __launch_bounds__(256) void k_gemm1(const float* __restrict__ X,
                                               const float* __restrict__ W1,
                                               __half* __restrict__ H) {
  __shared__ float xs[64 * 132];
  int tid = threadIdx.x;
  int row0 = blockIdx.x * 64;
  for (int i = tid; i < 64 * 32; i += 256) {
    int r = i >> 5, k4 = i & 31;
    float4 v = (row0 + r < NN) ? ((const float4*)X)[(size_t)(row0 + r) * 32 + k4]
                               : make_float4(0.f, 0.f, 0.f, 0.f);
    *(float4*)&xs[r * 132 + k4 * 4] = v;
  }
  __syncthreads();
  int cg = tid & 15, rg = tid >> 4;
  int f0 = cg * 8, r0 = rg * 4;
  float acc[4][8];
#pragma unroll
  for (int a = 0; a < 4; ++a)
#pragma unroll
    for (int b = 0; b < 8; ++b) acc[a][b] = 0.f;
  const float4* W4 = (const float4*)W1;
#pragma unroll 4
  for (int k = 0; k < 128; ++k) {
    float4 w0 = W4[k * 32 + (f0 >> 2)];
    float4 w1 = W4[k * 32 + (f0 >> 2) + 1];
    float wv[8] = {w0.x, w0.y, w0.z, w0.w, w1.x, w1.y, w1.z, w1.w};
    float xv[4];
#pragma unroll
    for (int a = 0; a < 4; ++a) xv[a] = xs[(r0 + a) * 132 + k];
#pragma unroll
    for (int a = 0; a < 4; ++a)
#pragma unroll
      for (int b = 0; b < 8; ++b) acc[a][b] += xv[a] * wv[b];
  }
#pragma unroll
  for (int a = 0; a < 4; ++a) {
    int r = row0 + r0 + a;
    if (r < NN) {
      H8 t;
      t.h[0] = __floats2half2_rn(acc[a][0], acc[a][1]);
      t.h[1] = __floats2half2_rn(acc[a][2], acc[a][3]);
      t.h[2] = __floats2half2_rn(acc[a][4], acc[a][5]);
      t.h[3] = __floats2half2_rn(acc[a][6], acc[a][7]);
      *(uint4*)&H[(size_t)r * 128 + f0] = t.u;
    }
  }
}

// pull-gather layer1: O[c,:] = b1 + sum H[r,:]*nm ; H is fp16, acc fp32
// 32 lanes x 4 halves (8B load) per node, 8 nodes per 256-block, unroll x2
__global__ __launch_bounds__(256) void k_gather1(const int* __restrict__ off,
                                                 const int2* __restrict__ sedge,
                                                 const __half* __restrict__ H,
                                                 const float* __restrict__ b1,
                                                 float* __restrict__ O) {
  int node = blockIdx.x * 8 + (threadIdx.x >> 5);
  int f4 = threadIdx.x & 31;
  const uint2* Hh = (const uint2*)H;  // 32 uint2 (4 halves) per row
  float4 acc = ((const float4*)b1)[f4];
  int j0 = off[node], j1 = off[node + 1];
  int j = j0;
  for (; j + 1 < j1; j += 2) {
    int2 e0 = sedge[j];
    int2 e1 = sedge[j + 1];
    uint2 r0 = Hh[(size_t)e0.x * 32 + f4];
    uint2 r1 = Hh[(size_t)e1.x * 32 + f4];
    float n0 = __int_as_float(e0.y), n1 = __int_as_float(e1.y);
    float2 a0 = __half22float2(*(__half2*)&r0.x);
    float2 b0 = __half22float2(*(__half2*)&r0.y);
    float2 a1 = __half22float2(*(__half2*)&r1.x);
    float2 b1v = __half22float2(*(__half2*)&r1.y);
    acc.x = fmaf(a0.x, n0, acc.x);
    acc.y = fmaf(a0.y, n0, acc.y);
    acc.z = fmaf(b0.x, n0, acc.z);
    acc.w = fmaf(b0.y, n0, acc.w);
    acc.x = fmaf(a1.x, n1, acc.x);
    acc.y = fmaf(a1.y, n1, acc.y);
    acc.z = fmaf(b1v.x, n1, acc.z);
    acc.w = fmaf(b1v.y, n1, acc.w);
  }
  if (j < j1) {
    int2 e = sedge[j];
    float nm = __int_as_float(e.y);
    uint2 r = Hh[(size_t)e.x * 32 + f4];
    float2 a = __half22float2(*(__half2*)&r.x);
    float2 b = __half22float2(*(__half2*)&r.y);
    acc.x = fmaf(a.x, nm, acc.x);
    acc.y = fmaf(a.y, nm, acc.y);
    acc.z = fmaf(b.x, nm, acc.z);
    acc.w = fmaf(b.y, nm, acc.w);
  }
  ((float4*)O)[(size_t)node * 32 + f4] = acc;
}

__global__ void k_stats(const float* __restrict__ X, float* __restrict__ sum,
                        float* __restrict__ sq, int C) {
  int f = threadIdx.x & (C - 1);
  int rg = threadIdx.x / C;
  int nrg = 256 / C;
  float s = 0.f, ss = 0.f;
  for (int r = blockIdx.x * nrg + rg; r < NN; r += gridDim.x * nrg) {
    float v = X[(size_t)r * C + f];
    s += v;
    ss += v * v;
  }
  __shared__ float ls[256], lss[256];
  ls[threadIdx.x] = s;
  lss[threadIdx.x] = ss;
  __syncthreads();
  if (rg == 0) {
    for (int g = 1; g < nrg; ++g) { s += ls[g * C + f]; ss += lss[g * C + f]; }
    atomicAdd(&sum[f], s);
    atomicAdd(&sq[f], ss);
  }
}

// GEMM2: H2[N,64](fp16) = leaky(BN1(O1)) @ W2[128,64]
__global__ __launch_bounds__(256) void k_gemm2(const float* __restrict__ O1,
                                               const float* __restrict__ W2,
                                               const float* __restrict__ sum1,
                                               const float* __restrict__ sq1,
                                               const float* __restrict__ g1,
                                               const float* __restrict__ be1,
                                               __half* __restrict__ H2) {
  __shared__ float xs[64 * 132];
  __shared__ float a1s[128], c1s[128];
  int tid = threadIdx.x;
  if (tid < 128) {
    float mu = sum1[tid] * (1.0f / NN);
    float var = sq1[tid] * (1.0f / NN) - mu * mu;
    float a = g1[tid] * rsqrtf(var + EPSB);
    a1s[tid] = a;
    c1s[tid] = be1[tid] - mu * a;
  }
  __syncthreads();
  int row0 = blockIdx.x * 64;
  for (int i = tid; i < 64 * 32; i += 256) {
    int r = i >> 5, k4 = i & 31;
    float4 v = (row0 + r < NN) ? ((const float4*)O1)[(size_t)(row0 + r) * 32 + k4]
                               : make_float4(0.f, 0.f, 0.f, 0.f);
    float4 a = *(const float4*)&a1s[k4 * 4];
    float4 c = *(const float4*)&c1s[k4 * 4];
    float4 y;
    y.x = fmaf(a.x, v.x, c.x);
    y.y = fmaf(a.y, v.y, c.y);
    y.z = fmaf(a.z, v.z, c.z);
    y.w = fmaf(a.w, v.w, c.w);
    y.x = y.x >= 0.f ? y.x : SLOPE * y.x;
    y.y = y.y >= 0.f ? y.y : SLOPE * y.y;
    y.z = y.z >= 0.f ? y.z : SLOPE * y.z;
    y.w = y.w >= 0.f ? y.w : SLOPE * y.w;
    *(float4*)&xs[r * 132 + k4 * 4] = y;
  }
  __syncthreads();
  int cg = tid & 7, rg = tid >> 3;
  int f0 = cg * 8, r0 = rg * 2;
  float acc[2][8];
#pragma unroll
  for (int a = 0; a < 2; ++a)
#pragma unroll
    for (int b = 0; b < 8; ++b) acc[a][b] = 0.f;
  const float4* W4 = (const float4*)W2;
#pragma unroll 4
  for (int k = 0; k < 128; ++k) {
    float4 w0 = W4[k * 16 + (f0 >> 2)];
    float4 w1 = W4[k * 16 + (f0 >> 2) + 1];
    float wv[8] = {w0.x, w0.y, w0.z, w0.w, w1.x, w1.y, w1.z, w1.w};
    float x0 = xs[(r0 + 0) * 132 + k];
    float x1 = xs[(r0 + 1) * 132 + k];
#pragma unroll
    for (int b = 0; b < 8; ++b) {
      acc[0][b] += x0 * wv[b];
      acc[1][b] += x1 * wv[b];
    }
  }
#pragma unroll
  for (int a = 0; a < 2; ++a) {
    int r = row0 + r0 + a;
    if (r < NN) {
      H8 t;
      t.h[0] = __floats2half2_rn(acc[a][0], acc[a][1]);
      t.h[1] = __floats2half2_rn(acc[a][2], acc[a][3]);
      t.h[2] = __floats2half2_rn(acc[a][4], acc[a][5]);
      t.h[3] = __floats2half2_rn(acc[a][6], acc[a][7]);
      *(uint4*)&H2[(size_t)r * 64 + f0] = t.u;
    }
  }
}

// pull-gather layer2: fp16 rows, 16 lanes x 4 halves per node, 16 nodes/block
__global__ __launch_bounds__(256) void k_gather2(const int* __restrict__ off,
                                                 const int2* __restrict__ sedge,
                                                 const __half* __restrict__ H,
                                                 const float* __restrict__ b2,
                                                 float* __restrict__ O) {
  int node = blockIdx.x * 16 + (threadIdx.x >> 4);
  int f4 = threadIdx.x & 15;
  const uint2* Hh = (const uint2*)H;  // 16 uint2 per row
  float4 acc = ((const float4*)b2)[f4];
  int j0 = off[node], j1 = off[node + 1];
  int j = j0;
  for (; j + 1 < j1; j += 2) {
    int2 e0 = sedge[j];
    int2 e1 = sedge[j + 1];
    uint2 r0 = Hh[(size_t)e0.x * 16 + f4];
    uint2 r1 = Hh[(size_t)e1.x * 16 + f4];
    float n0 = __int_as_float(e0.y), n1 = __int_as_float(e1.y);
    float2 a0 = __half22float2(*(__half2*)&r0.x);
    float2 b0 = __half22float2(*(__half2*)&r0.y);
    float2 a1 = __half22float2(*(__half2*)&r1.x);
    float2 b1v = __half22float2(*(__half2*)&r1.y);
    acc.x = fmaf(a0.x, n0, acc.x);
    acc.y = fmaf(a0.y, n0, acc.y);
    acc.z = fmaf(b0.x, n0, acc.z);
    acc.w = fmaf(b0.y, n0, acc.w);
    acc.x = fmaf(a1.x, n1, acc.x);
    acc.y = fmaf(a1.y, n1, acc.y);
    acc.z = fmaf(b1v.x, n1, acc.z);
    acc.w = fmaf(b1v.y, n1, acc.w);
  }
  if (j < j1) {
    int2 e = sedge[j];
    float nm = __int_as_float(e.y);
    uint2 r = Hh[(size_t)e.x * 16 + f4];
    float2 a = __half22float2(*(__half2*)&r.x);
    float2 b = __half22float2(*(__half2*)&r.y);
    acc.x = fmaf(a.x, nm, acc.x);
    acc.y = fmaf(a.y, nm, acc.y);
    acc.z = fmaf(b.x, nm, acc.z);
    acc.w = fmaf(b.y, nm, acc.w);
  }
  ((float4*)O)[(size_t)node * 16 + f4] = acc;
}

__global__ void k_final(float* __restrict__ O, const float* __restrict__ sum2,
                        const float* __restrict__ sq2, const float* __restrict__ g2,
                        const float* __restrict__ be2) {
  int i = blockIdx.x * 256 + threadIdx.x;
  if (i < NN * 64) {
    int f = i & 63;
    float mu = sum2[f] * (1.0f / NN);
    float var = sq2[f] * (1.0f / NN) - mu * mu;
    float a = g2[f] * rsqrtf(var + EPSB);
    float c = be2[f] - mu * a;
    O[i] = fmaf(a, O[i], c);
  }
}

extern "C" void kernel_launch(void* const* d_in, const int* in_sizes, int n_in,
                              void* d_out, int out_size, void* d_ws, size_t ws_size,
                              hipStream_t stream) {
  const int* adj = (const int*)d_in[0];
  const float* w = (const float*)d_in[1];
  const float* X = (const float*)d_in[2];
  const float* W1 = (const float*)d_in[3];
  const float* b1 = (const float*)d_in[4];
  const float* g1 = (const float*)d_in[5];
  const float* be1 = (const float*)d_in[6];
  const float* W2 = (const float*)d_in[7];
  const float* b2 = (const float*)d_in[8];
  const float* g2 = (const float*)d_in[9];
  const float* be2 = (const float*)d_in[10];
  float* ws = (float*)d_ws;
  float* out = (float*)d_out;

  int2* sedge = (int2*)(ws + W_SEDGE);
  int* off = (int*)(ws + W_OFF);
  int* part = (int*)(ws + W_PART);
  int* pos = (int*)(ws + W_POS);
  float* dis = ws + W_DIS;
  float* sum1 = ws + W_SUM1;
  float* sq1 = ws + W_SQ1;
  float* sum2 = ws + W_SUM2;
  float* sq2 = ws + W_SQ2;
  __half* H1h = (__half*)(ws + W_H1);
  __half* H2h = (__half*)(ws + W_H1);  // aliases H1 (dead after gather1)
  float* O1 = ws + W_O1;
  unsigned long long* pack = (unsigned long long*)(ws + W_PACK);

  // zero the pack array (aliases O1, re-zeroed every call) + BN stats
  hipMemsetAsync(pack, 0, (size_t)NN * 8, stream);
  hipMemsetAsync(sum1, 0, (size_t)(W_SQ2 + 64 - W_SUM1) * sizeof(float), stream);

  k_deg<<<(NE + 255) / 256, 256, 0, stream>>>(adj + NE, w, pack);
  k_scanA<<<NB, 256, 0, stream>>>(pack, part);
  k_scanB<<<1, 256, 0, stream>>>(part, off);
  k_scanC<<<NB, 256, 0, stream>>>(pack, part, pos, dis, off, sedge);
  k_bucket<<<(NE + 255) / 256, 256, 0, stream>>>(adj, w, dis, pos, sedge);

  k_gemm1<<<(NN + 63) / 64, 256, 0, stream>>>(X, W1, H1h);
  k_gather1<<<NN / 8, 256, 0, stream>>>(off, sedge, H1h, b1, O1);
  k_stats<<<512, 256, 0, stream>>>(O1, sum1, sq1, 128);

  k_gemm2<<<(NN + 63) / 64, 256, 0, stream>>>(O1, W2, sum1, sq1, g1, be1, H2h);
  k_gather2<<<NN / 16, 256, 0, stream>>>(off, sedge, H2h, b2, out);
  k_stats<<<512, 256, 0, stream>>>(out, sum2, sq2, 64);
  k_final<<<NN * 64 / 256, 256, 0, stream>>>(out, sum2, sq2, g2, be2);
}

// Round 7
// 366.508 us; speedup vs baseline: 6.2621x; 1.0097x over previous
//
#include <hip/hip_runtime.h>
#include <hip/hip_fp16.h>

#define NN 50000
#define NE 800000
#define NBKT 782          // ceil(NN/64) coarse buckets of 64 dests
#define CB 128            // count/scatter blocks
#define EPSB 1e-5f
#define SLOPE 0.01f
#define BCAP 2112         // LDS out-buffer cap per bucket (avg 1023+64, sigma~32)

// workspace layout (4-byte element offsets)
#define W_SEDGE 0          // NE+NN u32  = 850,000
#define W_OFF   850000     // NN+1 ints
#define W_TB    900004     // NBKT+1 ints
#define W_DIS   900800     // NN floats
#define W_SUM1  950800     // 128
#define W_SQ1   950928     // 128
#define W_SUM2  951056     // 64
#define W_SQ2   951120     // 64
#define W_HIST  951296     // NBKT*CB = 100,096 ints
#define W_TEMP  1051392    // NE int2 = 1,600,000 ints (8B aligned: even offset)
#define W_H1    2651392    // N*128 fp16 = 3,200,000 float slots (H2 aliases)
#define W_O1    5851392    // N*128 floats

union H8 { uint4 u; __half2 h[4]; };

// pass A: per-block LDS histogram of coarse destination buckets
__global__ __launch_bounds__(256) void k_countA(const int* __restrict__ col,
                                                int* __restrict__ hist) {
  __shared__ int h[NBKT];
  for (int i = threadIdx.x; i < NBKT; i += 256) h[i] = 0;
  __syncthreads();
  const int per = (NE + CB - 1) / CB;
  int lo = blockIdx.x * per, hi = min(lo + per, NE);
  for (int e = lo + threadIdx.x; e < hi; e += 256)
    atomicAdd(&h[col[e] >> 6], 1);
  __syncthreads();
  for (int i = threadIdx.x; i < NBKT; i += 256)
    hist[i * CB + blockIdx.x] = h[i];
}

// pass B: scan hist (bucket-major) -> per-(bucket,block) bases; bucket totals tb[]
__global__ __launch_bounds__(1024) void k_scanH(int* __restrict__ hist,
                                                int* __restrict__ tb,
                                                int* __restrict__ off) {
  int t = threadIdx.x;
  int total = 0;
  if (t < NBKT)
    for (int i = 0; i < CB; ++i) total += hist[t * CB + i];
  __shared__ int ls[1024];
  ls[t] = (t < NBKT) ? total : 0;
  __syncthreads();
  for (int o = 1; o < 1024; o <<= 1) {
    int v = (t >= o) ? ls[t - o] : 0;
    __syncthreads();
    ls[t] += v;
    __syncthreads();
  }
  if (t < NBKT) {
    int run = ls[t] - total;  // exclusive prefix = bucket base in temp
    tb[t] = run;
    for (int i = 0; i < CB; ++i) {
      int c = hist[t * CB + i];
      hist[t * CB + i] = run;
      run += c;
    }
  }
  if (t == 0) { tb[NBKT] = NE; off[NN] = NE + NN; }
}

// pass C: scatter edges into coarse-binned temp: (src<<6|dst_local, w)
__global__ __launch_bounds__(256) void k_scatC(const int* __restrict__ adj,
                                               const float* __restrict__ w,
                                               const int* __restrict__ hist,
                                               int2* __restrict__ temp) {
  __shared__ int cur[NBKT];
  for (int i = threadIdx.x; i < NBKT; i += 256) cur[i] = hist[i * CB + blockIdx.x];
  __syncthreads();
  const int per = (NE + CB - 1) / CB;
  int lo = blockIdx.x * per, hi = min(lo + per, NE);
  for (int e = lo + threadIdx.x; e < hi; e += 256) {
    int r = adj[e], c = adj[NE + e];
    int slot = atomicAdd(&cur[c >> 6], 1);
    temp[slot] = make_int2((r << 6) | (c & 63), __float_as_int(w[e]));
  }
}

// pass D: one block per coarse bucket. LDS per-dest count + weight sum
// (this IS the degree computation), dis=rsqrt(deg+1), CSR off, group edges
// per dest with self edge (src=dest, w=1.0) in slot 0, coalesced write-out.
__global__ __launch_bounds__(256) void k_binD(const int2* __restrict__ temp,
                                              const int* __restrict__ tb,
                                              float* __restrict__ dis,
                                              int* __restrict__ off,
                                              unsigned* __restrict__ sedge) {
  int k = blockIdx.x;
  int tb0 = tb[k];
  int Tk = tb[k + 1] - tb0;
  int d0 = k << 6;
  int nd = min(64, NN - d0);
  int fbase = tb0 + d0;  // d0 = 64*k self slots before this bucket
  __shared__ int cnt[64];
  __shared__ float wsum[64];
  __shared__ int lpos[64];
  __shared__ unsigned ob[BCAP];
  if (threadIdx.x < 64) { cnt[threadIdx.x] = 0; wsum[threadIdx.x] = 0.f; }
  __syncthreads();
  for (int i = threadIdx.x; i < Tk; i += 256) {
    int2 e = temp[tb0 + i];
    int dl = e.x & 63;
    atomicAdd(&cnt[dl], 1);
    atomicAdd(&wsum[dl], __int_as_float(e.y));
  }
  __syncthreads();
  if (threadIdx.x < 64 && threadIdx.x < nd)
    dis[d0 + threadIdx.x] = rsqrtf(wsum[threadIdx.x] + 1.0f);
  if (threadIdx.x == 0) {
    int run = 0;
    for (int d = 0; d < nd; ++d) {
      off[d0 + d] = fbase + run;
      ob[run] = ((unsigned)(d0 + d) << 16) | 0x3C00u;  // self: fp16(1.0)
      lpos[d] = run + 1;
      run += cnt[d] + 1;
    }
  }
  __syncthreads();
  for (int i = threadIdx.x; i < Tk; i += 256) {
    int2 e = temp[tb0 + i];
    int dl = e.x & 63;
    unsigned src = ((unsigned)e.x) >> 6;
    int slot = atomicAdd(&lpos[dl], 1);
    __half hw = __float2half(__int_as_float(e.y));
    if (slot < BCAP)
      ob[slot] = (src << 16) | (unsigned)__half_as_ushort(hw);
  }
  __syncthreads();
  int tot = min(Tk + nd, BCAP);
  for (int i = threadIdx.x; i < tot; i += 256)
    sedge[fbase + i] = ob[i];
}

// GEMM1: H[N,128](fp16) = X[N,128] @ W1[128,128]
__global__ __launch_bounds__(256) void k_gemm1(const float* __restrict__ X,
                                               const float* __restrict__ W1,
                                               __half* __restrict__ H) {
  __shared__ float xs[64 * 132];
  int tid = threadIdx.x;
  int row0 = blockIdx.x * 64;
  for (int i = tid; i < 64 * 32; i += 256) {
    int r = i >> 5, k4 = i & 31;
    float4 v = (row0 + r < NN) ? ((const float4*)X)[(size_t)(row0 + r) * 32 + k4]
                               : make_float4(0.f, 0.f, 0.f, 0.f);
    *(float4*)&xs[r * 132 + k4 * 4] = v;
  }
  __syncthreads();
  int cg = tid & 15, rg = tid >> 4;
  int f0 = cg * 8, r0 = rg * 4;
  float acc[4][8];
#pragma unroll
  for (int a = 0; a < 4; ++a)
#pragma unroll
    for (int b = 0; b < 8; ++b) acc[a][b] = 0.f;
  const float4* W4 = (const float4*)W1;
#pragma unroll 4
  for (int k = 0; k < 128; ++k) {
    float4 w0 = W4[k * 32 + (f0 >> 2)];
    float4 w1 = W4[k * 32 + (f0 >> 2) + 1];
    float wv[8] = {w0.x, w0.y, w0.z, w0.w, w1.x, w1.y, w1.z, w1.w};
    float xv[4];
#pragma unroll
    for (int a = 0; a < 4; ++a) xv[a] = xs[(r0 + a) * 132 + k];
#pragma unroll
    for (int a = 0; a < 4; ++a)
#pragma unroll
      for (int b = 0; b < 8; ++b) acc[a][b] += xv[a] * wv[b];
  }
#pragma unroll
  for (int a = 0; a < 4; ++a) {
    int r = row0 + r0 + a;
    if (r < NN) {
      H8 t;
      t.h[0] = __floats2half2_rn(acc[a][0], acc[a][1]);
      t.h[1] = __floats2half2_rn(acc[a][2], acc[a][3]);
      t.h[2] = __floats2half2_rn(acc[a][4], acc[a][5]);
      t.h[3] = __floats2half2_rn(acc[a][6], acc[a][7]);
      *(uint4*)&H[(size_t)r * 128 + f0] = t.u;
    }
  }
}

// pull-gather layer1: O[c,:] = b1 + sum dis[src]*w*dis[c] * H[src,:]
__global__ __launch_bounds__(256) void k_gather1(const int* __restrict__ off,
                                                 const unsigned* __restrict__ sedge,
                                                 const float* __restrict__ dis,
                                                 const __half* __restrict__ H,
                                                 const float* __restrict__ b1,
                                                 float* __restrict__ O) {
  int node = blockIdx.x * 8 + (threadIdx.x >> 5);
  int f4 = threadIdx.x & 31;
  const uint2* Hh = (const uint2*)H;
  float4 acc = ((const float4*)b1)[f4];
  float dc = dis[node];
  int j0 = off[node], j1 = off[node + 1];
  int j = j0;
  for (; j + 1 < j1; j += 2) {
    unsigned u0 = sedge[j], u1 = sedge[j + 1];
    unsigned s0 = u0 >> 16, s1 = u1 >> 16;
    uint2 r0 = Hh[(size_t)s0 * 32 + f4];
    uint2 r1 = Hh[(size_t)s1 * 32 + f4];
    float n0 = dis[s0] * __half2float(__ushort_as_half((unsigned short)(u0 & 0xFFFFu))) * dc;
    float n1 = dis[s1] * __half2float(__ushort_as_half((unsigned short)(u1 & 0xFFFFu))) * dc;
    float2 a0 = __half22float2(*(__half2*)&r0.x);
    float2 b0 = __half22float2(*(__half2*)&r0.y);
    float2 a1 = __half22float2(*(__half2*)&r1.x);
    float2 b1v = __half22float2(*(__half2*)&r1.y);
    acc.x = fmaf(a0.x, n0, acc.x);
    acc.y = fmaf(a0.y, n0, acc.y);
    acc.z = fmaf(b0.x, n0, acc.z);
    acc.w = fmaf(b0.y, n0, acc.w);
    acc.x = fmaf(a1.x, n1, acc.x);
    acc.y = fmaf(a1.y, n1, acc.y);
    acc.z = fmaf(b1v.x, n1, acc.z);
    acc.w = fmaf(b1v.y, n1, acc.w);
  }
  if (j < j1) {
    unsigned u = sedge[j];
    unsigned s = u >> 16;
    uint2 r = Hh[(size_t)s * 32 + f4];
    float nm = dis[s] * __half2float(__ushort_as_half((unsigned short)(u & 0xFFFFu))) * dc;
    float2 a = __half22float2(*(__half2*)&r.x);
    float2 b = __half22float2(*(__half2*)&r.y);
    acc.x = fmaf(a.x, nm, acc.x);
    acc.y = fmaf(a.y, nm, acc.y);
    acc.z = fmaf(b.x, nm, acc.z);
    acc.w = fmaf(b.y, nm, acc.w);
  }
  ((float4*)O)[(size_t)node * 32 + f4] = acc;
}

__global__ void k_stats(const float* __restrict__ X, float* __restrict__ sum,
                        float* __restrict__ sq, int C) {
  int f = threadIdx.x & (C - 1);
  int rg = threadIdx.x / C;
  int nrg = 256 / C;
  float s = 0.f, ss = 0.f;
  for (int r = blockIdx.x * nrg + rg; r < NN; r += gridDim.x * nrg) {
    float v = X[(size_t)r * C + f];
    s += v;
    ss += v * v;
  }
  __shared__ float ls[256], lss[256];
  ls[threadIdx.x] = s;
  lss[threadIdx.x] = ss;
  __syncthreads();
  if (rg == 0) {
    for (int g = 1; g < nrg; ++g) { s += ls[g * C + f]; ss += lss[g * C + f]; }
    atomicAdd(&sum[f], s);
    atomicAdd(&sq[f], ss);
  }
}

// GEMM2: H2[N,64](fp16) = leaky(BN1(O1)) @ W2[128,64]
__global__ __launch_bounds__(256) void k_gemm2(const float* __restrict__ O1,
                                               const float* __restrict__ W2,
                                               const float* __restrict__ sum1,
                                               const float* __restrict__ sq1,
                                               const float* __restrict__ g1,
                                               const float* __restrict__ be1,
                                               __half* __restrict__ H2) {
  __shared__ float xs[64 * 132];
  __shared__ float a1s[128], c1s[128];
  int tid = threadIdx.x;
  if (tid < 128) {
    float mu = sum1[tid] * (1.0f / NN);
    float var = sq1[tid] * (1.0f / NN) - mu * mu;
    float a = g1[tid] * rsqrtf(var + EPSB);
    a1s[tid] = a;
    c1s[tid] = be1[tid] - mu * a;
  }
  __syncthreads();
  int row0 = blockIdx.x * 64;
  for (int i = tid; i < 64 * 32; i += 256) {
    int r = i >> 5, k4 = i & 31;
    float4 v = (row0 + r < NN) ? ((const float4*)O1)[(size_t)(row0 + r) * 32 + k4]
                               : make_float4(0.f, 0.f, 0.f, 0.f);
    float4 a = *(const float4*)&a1s[k4 * 4];
    float4 c = *(const float4*)&c1s[k4 * 4];
    float4 y;
    y.x = fmaf(a.x, v.x, c.x);
    y.y = fmaf(a.y, v.y, c.y);
    y.z = fmaf(a.z, v.z, c.z);
    y.w = fmaf(a.w, v.w, c.w);
    y.x = y.x >= 0.f ? y.x : SLOPE * y.x;
    y.y = y.y >= 0.f ? y.y : SLOPE * y.y;
    y.z = y.z >= 0.f ? y.z : SLOPE * y.z;
    y.w = y.w >= 0.f ? y.w : SLOPE * y.w;
    *(float4*)&xs[r * 132 + k4 * 4] = y;
  }
  __syncthreads();
  int cg = tid & 7, rg = tid >> 3;
  int f0 = cg * 8, r0 = rg * 2;
  float acc[2][8];
#pragma unroll
  for (int a = 0; a < 2; ++a)
#pragma unroll
    for (int b = 0; b < 8; ++b) acc[a][b] = 0.f;
  const float4* W4 = (const float4*)W2;
#pragma unroll 4
  for (int k = 0; k < 128; ++k) {
    float4 w0 = W4[k * 16 + (f0 >> 2)];
    float4 w1 = W4[k * 16 + (f0 >> 2) + 1];
    float wv[8] = {w0.x, w0.y, w0.z, w0.w, w1.x, w1.y, w1.z, w1.w};
    float x0 = xs[(r0 + 0) * 132 + k];
    float x1 = xs[(r0 + 1) * 132 + k];
#pragma unroll
    for (int b = 0; b < 8; ++b) {
      acc[0][b] += x0 * wv[b];
      acc[1][b] += x1 * wv[b];
    }
  }
#pragma unroll
  for (int a = 0; a < 2; ++a) {
    int r = row0 + r0 + a;
    if (r < NN) {
      H8 t;
      t.h[0] = __floats2half2_rn(acc[a][0], acc[a][1]);
      t.h[1] = __floats2half2_rn(acc[a][2], acc[a][3]);
      t.h[2] = __floats2half2_rn(acc[a][4], acc[a][5]);
      t.h[3] = __floats2half2_rn(acc[a][6], acc[a][7]);
      *(uint4*)&H2[(size_t)r * 64 + f0] = t.u;
    }
  }
}

// pull-gather layer2: fp16 rows, 16 lanes x 4 halves per node
__global__ __launch_bounds__(256) void k_gather2(const int* __restrict__ off,
                                                 const unsigned* __restrict__ sedge,
                                                 const float* __restrict__ dis,
                                                 const __half* __restrict__ H,
                                                 const float* __restrict__ b2,
                                                 float* __restrict__ O) {
  int node = blockIdx.x * 16 + (threadIdx.x >> 4);
  int f4 = threadIdx.x & 15;
  const uint2* Hh = (const uint2*)H;
  float4 acc = ((const float4*)b2)[f4];
  float dc = dis[node];
  int j0 = off[node], j1 = off[node + 1];
  int j = j0;
  for (; j + 1 < j1; j += 2) {
    unsigned u0 = sedge[j], u1 = sedge[j + 1];
    unsigned s0 = u0 >> 16, s1 = u1 >> 16;
    uint2 r0 = Hh[(size_t)s0 * 16 + f4];
    uint2 r1 = Hh[(size_t)s1 * 16 + f4];
    float n0 = dis[s0] * __half2float(__ushort_as_half((unsigned short)(u0 & 0xFFFFu))) * dc;
    float n1 = dis[s1] * __half2float(__ushort_as_half((unsigned short)(u1 & 0xFFFFu))) * dc;
    float2 a0 = __half22float2(*(__half2*)&r0.x);
    float2 b0 = __half22float2(*(__half2*)&r0.y);
    float2 a1 = __half22float2(*(__half2*)&r1.x);
    float2 b1v = __half22float2(*(__half2*)&r1.y);
    acc.x = fmaf(a0.x, n0, acc.x);
    acc.y = fmaf(a0.y, n0, acc.y);
    acc.z = fmaf(b0.x, n0, acc.z);
    acc.w = fmaf(b0.y, n0, acc.w);
    acc.x = fmaf(a1.x, n1, acc.x);
    acc.y = fmaf(a1.y, n1, acc.y);
    acc.z = fmaf(b1v.x, n1, acc.z);
    acc.w = fmaf(b1v.y, n1, acc.w);
  }
  if (j < j1) {
    unsigned u = sedge[j];
    unsigned s = u >> 16;
    uint2 r = Hh[(size_t)s * 16 + f4];
    float nm = dis[s] * __half2float(__ushort_as_half((unsigned short)(u & 0xFFFFu))) * dc;
    float2 a = __half22float2(*(__half2*)&r.x);
    float2 b = __half22float2(*(__half2*)&r.y);
    acc.x = fmaf(a.x, nm, acc.x);
    acc.y = fmaf(a.y, nm, acc.y);
    acc.z = fmaf(b.x, nm, acc.z);
    acc.w = fmaf(b.y, nm, acc.w);
  }
  ((float4*)O)[(size_t)node * 16 + f4] = acc;
}

__global__ void k_final(float* __restrict__ O, const float* __restrict__ sum2,
                        const float* __restrict__ sq2, const float* __restrict__ g2,
                        const float* __restrict__ be2) {
  int i = blockIdx.x * 256 + threadIdx.x;
  if (i < NN * 64) {
    int f = i & 63;
    float mu = sum2[f] * (1.0f / NN);
    float var = sq2[f] * (1.0f / NN) - mu * mu;
    float a = g2[f] * rsqrtf(var + EPSB);
    float c = be2[f] - mu * a;
    O[i] = fmaf(a, O[i], c);
  }
}

extern "C" void kernel_launch(void* const* d_in, const int* in_sizes, int n_in,
                              void* d_out, int out_size, void* d_ws, size_t ws_size,
                              hipStream_t stream) {
  const int* adj = (const int*)d_in[0];
  const float* w = (const float*)d_in[1];
  const float* X = (const float*)d_in[2];
  const float* W1 = (const float*)d_in[3];
  const float* b1 = (const float*)d_in[4];
  const float* g1 = (const float*)d_in[5];
  const float* be1 = (const float*)d_in[6];
  const float* W2 = (const float*)d_in[7];
  const float* b2 = (const float*)d_in[8];
  const float* g2 = (const float*)d_in[9];
  const float* be2 = (const float*)d_in[10];
  float* ws = (float*)d_ws;
  float* out = (float*)d_out;

  unsigned* sedge = (unsigned*)(ws + W_SEDGE);
  int* off = (int*)(ws + W_OFF);
  int* tb = (int*)(ws + W_TB);
  float* dis = ws + W_DIS;
  float* sum1 = ws + W_SUM1;
  float* sq1 = ws + W_SQ1;
  float* sum2 = ws + W_SUM2;
  float* sq2 = ws + W_SQ2;
  int* hist = (int*)(ws + W_HIST);
  int2* temp = (int2*)(ws + W_TEMP);
  __half* H1h = (__half*)(ws + W_H1);
  __half* H2h = (__half*)(ws + W_H1);  // aliases H1 (dead after gather1)
  float* O1 = ws + W_O1;

  // zero BN stats only (everything else is fully written before read)
  hipMemsetAsync(sum1, 0, (size_t)(W_SQ2 + 64 - W_SUM1) * sizeof(float), stream);

  k_countA<<<CB, 256, 0, stream>>>(adj + NE, hist);
  k_scanH<<<1, 1024, 0, stream>>>(hist, tb, off);
  k_scatC<<<CB, 256, 0, stream>>>(adj, w, hist, temp);
  k_binD<<<NBKT, 256, 0, stream>>>(temp, tb, dis, off, sedge);

  k_gemm1<<<(NN + 63) / 64, 256, 0, stream>>>(X, W1, H1h);
  k_gather1<<<NN / 8, 256, 0, stream>>>(off, sedge, dis, H1h, b1, O1);
  k_stats<<<512, 256, 0, stream>>>(O1, sum1, sq1, 128);

  k_gemm2<<<(NN + 63) / 64, 256, 0, stream>>>(O1, W2, sum1, sq1, g1, be1, H2h);
  k_gather2<<<NN / 16, 256, 0, stream>>>(off, sedge, dis, H2h, b2, out);
  k_stats<<<512, 256, 0, stream>>>(out, sum2, sq2, 64);
  k_final<<<NN * 64 / 256, 256, 0, stream>>>(out, sum2, sq2, g2, be2);
}

// Round 8
// 345.506 us; speedup vs baseline: 6.6428x; 1.0608x over previous
//
#include <hip/hip_runtime.h>
#include <hip/hip_fp16.h>

#define NN 50000
#define NE 800000
#define NBKT 782          // ceil(NN/64) coarse buckets of 64 dests
#define CB 128            // count/scatter blocks
#define EPSB 1e-5f
#define SLOPE 0.01f
#define BCAP 2112         // LDS out-buffer cap per bucket (avg 1023+64)

// workspace layout (4-byte element offsets)
#define W_SEDGE 0          // NE+NN u32 = 850,000
#define W_OFF   850000     // NN+1 ints
#define W_TB    900004     // NBKT+1 ints
#define W_DIS   900800     // NN floats
#define W_SUM1  950800     // 128
#define W_SQ1   950928     // 128
#define W_SUM2  951056     // 64
#define W_SQ2   951120     // 64
#define W_HIST  951296     // CB*NBKT = 100,096 ints (block-major)
#define W_TEMP  1051392    // NE int2 = 1,600,000 ints (8B aligned)
#define W_H1    2651392    // N*128 fp16 = 3.2M float slots (H2 aliases)
#define W_O1    5851392    // N*128 fp16 = 3.2M float slots

union H8 { uint4 u; __half2 h[4]; };

// pass A: per-block LDS histogram; block-major output (coalesced)
__global__ __launch_bounds__(256) void k_countA(const int* __restrict__ col,
                                                int* __restrict__ hist) {
  __shared__ int h[NBKT];
  for (int i = threadIdx.x; i < NBKT; i += 256) h[i] = 0;
  __syncthreads();
  const int per = (NE + CB - 1) / CB;
  int lo = blockIdx.x * per, hi = min(lo + per, NE);
  for (int e = lo + threadIdx.x; e < hi; e += 256)
    atomicAdd(&h[col[e] >> 6], 1);
  __syncthreads();
  for (int i = threadIdx.x; i < NBKT; i += 256)
    hist[blockIdx.x * NBKT + i] = h[i];
}

// pass B: column sums (coalesced), scan over buckets, base rewrite (coalesced)
__global__ __launch_bounds__(1024) void k_scanH(int* __restrict__ hist,
                                                int* __restrict__ tb,
                                                int* __restrict__ off) {
  int t = threadIdx.x;
  int total = 0;
  if (t < NBKT)
    for (int i = 0; i < CB; ++i) total += hist[i * NBKT + t];
  __shared__ int ls[1024];
  ls[t] = (t < NBKT) ? total : 0;
  __syncthreads();
  for (int o = 1; o < 1024; o <<= 1) {
    int v = (t >= o) ? ls[t - o] : 0;
    __syncthreads();
    ls[t] += v;
    __syncthreads();
  }
  if (t < NBKT) {
    int run = ls[t] - total;  // exclusive prefix = bucket base in temp
    tb[t] = run;
    for (int i = 0; i < CB; ++i) {
      int c = hist[i * NBKT + t];
      hist[i * NBKT + t] = run;
      run += c;
    }
  }
  if (t == 0) { tb[NBKT] = NE; off[NN] = NE + NN; }
}

// pass C: scatter edges into coarse-binned temp: (src<<6|dst_local, w)
__global__ __launch_bounds__(256) void k_scatC(const int* __restrict__ adj,
                                               const float* __restrict__ w,
                                               const int* __restrict__ hist,
                                               int2* __restrict__ temp) {
  __shared__ int cur[NBKT];
  for (int i = threadIdx.x; i < NBKT; i += 256)
    cur[i] = hist[blockIdx.x * NBKT + i];
  __syncthreads();
  const int per = (NE + CB - 1) / CB;
  int lo = blockIdx.x * per, hi = min(lo + per, NE);
  for (int e = lo + threadIdx.x; e < hi; e += 256) {
    int r = adj[e], c = adj[NE + e];
    int slot = atomicAdd(&cur[c >> 6], 1);
    temp[slot] = make_int2((r << 6) | (c & 63), __float_as_int(w[e]));
  }
}

// pass D: one block per bucket; LDS per-dest count+wsum (degree), dis,
// wave-parallel offset scan, group edges with self edge in slot 0.
__global__ __launch_bounds__(256) void k_binD(const int2* __restrict__ temp,
                                              const int* __restrict__ tb,
                                              float* __restrict__ dis,
                                              int* __restrict__ off,
                                              unsigned* __restrict__ sedge) {
  int k = blockIdx.x;
  int tb0 = tb[k];
  int Tk = tb[k + 1] - tb0;
  int d0 = k << 6;
  int nd = min(64, NN - d0);
  int fbase = tb0 + d0;
  __shared__ int cnt[64];
  __shared__ float wsum[64];
  __shared__ int lpos[64];
  __shared__ unsigned ob[BCAP];
  if (threadIdx.x < 64) { cnt[threadIdx.x] = 0; wsum[threadIdx.x] = 0.f; }
  __syncthreads();
  for (int i = threadIdx.x; i < Tk; i += 256) {
    int2 e = temp[tb0 + i];
    int dl = e.x & 63;
    atomicAdd(&cnt[dl], 1);
    atomicAdd(&wsum[dl], __int_as_float(e.y));
  }
  __syncthreads();
  if (threadIdx.x < 64) {  // wave 0: parallel exclusive scan of cnt+1
    int lane = threadIdx.x;
    int c = (lane < nd) ? cnt[lane] + 1 : 0;
    int v = c;
#pragma unroll
    for (int o = 1; o < 64; o <<= 1) {
      int u = __shfl_up(v, o, 64);
      if (lane >= o) v += u;
    }
    int base = v - c;  // exclusive
    if (lane < nd) {
      dis[d0 + lane] = rsqrtf(wsum[lane] + 1.0f);
      off[d0 + lane] = fbase + base;
      ob[base] = ((unsigned)(d0 + lane) << 16) | 0x3C00u;  // self: fp16(1.0)
      lpos[lane] = base + 1;
    }
  }
  __syncthreads();
  for (int i = threadIdx.x; i < Tk; i += 256) {
    int2 e = temp[tb0 + i];
    int dl = e.x & 63;
    unsigned src = ((unsigned)e.x) >> 6;
    int slot = atomicAdd(&lpos[dl], 1);
    __half hw = __float2half(__int_as_float(e.y));
    if (slot < BCAP)
      ob[slot] = (src << 16) | (unsigned)__half_as_ushort(hw);
  }
  __syncthreads();
  int tot = min(Tk + nd, BCAP);
  for (int i = threadIdx.x; i < tot; i += 256)
    sedge[fbase + i] = ob[i];
}

// GEMM1: H[N,128](fp16) = X[N,128] @ W1[128,128]
__global__ __launch_bounds__(256) void k_gemm1(const float* __restrict__ X,
                                               const float* __restrict__ W1,
                                               __half* __restrict__ H) {
  __shared__ float xs[64 * 132];
  int tid = threadIdx.x;
  int row0 = blockIdx.x * 64;
  for (int i = tid; i < 64 * 32; i += 256) {
    int r = i >> 5, k4 = i & 31;
    float4 v = (row0 + r < NN) ? ((const float4*)X)[(size_t)(row0 + r) * 32 + k4]
                               : make_float4(0.f, 0.f, 0.f, 0.f);
    *(float4*)&xs[r * 132 + k4 * 4] = v;
  }
  __syncthreads();
  int cg = tid & 15, rg = tid >> 4;
  int f0 = cg * 8, r0 = rg * 4;
  float acc[4][8];
#pragma unroll
  for (int a = 0; a < 4; ++a)
#pragma unroll
    for (int b = 0; b < 8; ++b) acc[a][b] = 0.f;
  const float4* W4 = (const float4*)W1;
#pragma unroll 4
  for (int k = 0; k < 128; ++k) {
    float4 w0 = W4[k * 32 + (f0 >> 2)];
    float4 w1 = W4[k * 32 + (f0 >> 2) + 1];
    float wv[8] = {w0.x, w0.y, w0.z, w0.w, w1.x, w1.y, w1.z, w1.w};
    float xv[4];
#pragma unroll
    for (int a = 0; a < 4; ++a) xv[a] = xs[(r0 + a) * 132 + k];
#pragma unroll
    for (int a = 0; a < 4; ++a)
#pragma unroll
      for (int b = 0; b < 8; ++b) acc[a][b] += xv[a] * wv[b];
  }
#pragma unroll
  for (int a = 0; a < 4; ++a) {
    int r = row0 + r0 + a;
    if (r < NN) {
      H8 t;
      t.h[0] = __floats2half2_rn(acc[a][0], acc[a][1]);
      t.h[1] = __floats2half2_rn(acc[a][2], acc[a][3]);
      t.h[2] = __floats2half2_rn(acc[a][4], acc[a][5]);
      t.h[3] = __floats2half2_rn(acc[a][6], acc[a][7]);
      *(uint4*)&H[(size_t)r * 128 + f0] = t.u;
    }
  }
}

// pull-gather layer1: O(fp16)[c,:] = b1 + sum dis[s]*w*dis[c] * H[s,:]
__global__ __launch_bounds__(256) void k_gather1(const int* __restrict__ off,
                                                 const unsigned* __restrict__ sedge,
                                                 const float* __restrict__ dis,
                                                 const __half* __restrict__ H,
                                                 const float* __restrict__ b1,
                                                 __half* __restrict__ O) {
  int node = blockIdx.x * 8 + (threadIdx.x >> 5);
  int f4 = threadIdx.x & 31;
  const uint2* Hh = (const uint2*)H;
  float4 acc = ((const float4*)b1)[f4];
  float dc = dis[node];
  int j0 = off[node], j1 = off[node + 1];
  int j = j0;
  for (; j + 1 < j1; j += 2) {
    unsigned u0 = sedge[j], u1 = sedge[j + 1];
    unsigned s0 = u0 >> 16, s1 = u1 >> 16;
    uint2 r0 = Hh[(size_t)s0 * 32 + f4];
    uint2 r1 = Hh[(size_t)s1 * 32 + f4];
    float n0 = dis[s0] * __half2float(__ushort_as_half((unsigned short)(u0 & 0xFFFFu))) * dc;
    float n1 = dis[s1] * __half2float(__ushort_as_half((unsigned short)(u1 & 0xFFFFu))) * dc;
    float2 a0 = __half22float2(*(__half2*)&r0.x);
    float2 b0 = __half22float2(*(__half2*)&r0.y);
    float2 a1 = __half22float2(*(__half2*)&r1.x);
    float2 b1v = __half22float2(*(__half2*)&r1.y);
    acc.x = fmaf(a0.x, n0, acc.x);
    acc.y = fmaf(a0.y, n0, acc.y);
    acc.z = fmaf(b0.x, n0, acc.z);
    acc.w = fmaf(b0.y, n0, acc.w);
    acc.x = fmaf(a1.x, n1, acc.x);
    acc.y = fmaf(a1.y, n1, acc.y);
    acc.z = fmaf(b1v.x, n1, acc.z);
    acc.w = fmaf(b1v.y, n1, acc.w);
  }
  if (j < j1) {
    unsigned u = sedge[j];
    unsigned s = u >> 16;
    uint2 r = Hh[(size_t)s * 32 + f4];
    float nm = dis[s] * __half2float(__ushort_as_half((unsigned short)(u & 0xFFFFu))) * dc;
    float2 a = __half22float2(*(__half2*)&r.x);
    float2 b = __half22float2(*(__half2*)&r.y);
    acc.x = fmaf(a.x, nm, acc.x);
    acc.y = fmaf(a.y, nm, acc.y);
    acc.z = fmaf(b.x, nm, acc.z);
    acc.w = fmaf(b.y, nm, acc.w);
  }
  uint2 o;
  *(__half2*)&o.x = __floats2half2_rn(acc.x, acc.y);
  *(__half2*)&o.y = __floats2half2_rn(acc.z, acc.w);
  ((uint2*)O)[(size_t)node * 32 + f4] = o;
}

// column stats over fp16 [NN,128] matrix
__global__ __launch_bounds__(256) void k_statsh(const __half* __restrict__ X,
                                                float* __restrict__ sum,
                                                float* __restrict__ sq) {
  int f2 = threadIdx.x & 63;   // half2 feature pair
  int rg = threadIdx.x >> 6;   // 4 row groups
  float sx = 0.f, sy = 0.f, ssx = 0.f, ssy = 0.f;
  const unsigned* X2 = (const unsigned*)X;
  for (int r = blockIdx.x * 4 + rg; r < NN; r += gridDim.x * 4) {
    unsigned u = X2[(size_t)r * 64 + f2];
    float2 v = __half22float2(*(__half2*)&u);
    sx += v.x; sy += v.y;
    ssx += v.x * v.x; ssy += v.y * v.y;
  }
  __shared__ float ls[256][4];
  ls[threadIdx.x][0] = sx; ls[threadIdx.x][1] = sy;
  ls[threadIdx.x][2] = ssx; ls[threadIdx.x][3] = ssy;
  __syncthreads();
  if (rg == 0) {
    for (int g = 1; g < 4; ++g) {
      sx += ls[g * 64 + f2][0]; sy += ls[g * 64 + f2][1];
      ssx += ls[g * 64 + f2][2]; ssy += ls[g * 64 + f2][3];
    }
    atomicAdd(&sum[2 * f2], sx);
    atomicAdd(&sum[2 * f2 + 1], sy);
    atomicAdd(&sq[2 * f2], ssx);
    atomicAdd(&sq[2 * f2 + 1], ssy);
  }
}

__global__ void k_stats(const float* __restrict__ X, float* __restrict__ sum,
                        float* __restrict__ sq, int C) {
  int f = threadIdx.x & (C - 1);
  int rg = threadIdx.x / C;
  int nrg = 256 / C;
  float s = 0.f, ss = 0.f;
  for (int r = blockIdx.x * nrg + rg; r < NN; r += gridDim.x * nrg) {
    float v = X[(size_t)r * C + f];
    s += v;
    ss += v * v;
  }
  __shared__ float ls[256], lss[256];
  ls[threadIdx.x] = s;
  lss[threadIdx.x] = ss;
  __syncthreads();
  if (rg == 0) {
    for (int g = 1; g < nrg; ++g) { s += ls[g * C + f]; ss += lss[g * C + f]; }
    atomicAdd(&sum[f], s);
    atomicAdd(&sq[f], ss);
  }
}

// GEMM2: H2[N,64](fp16) = leaky(BN1(O1 fp16)) @ W2[128,64]
__global__ __launch_bounds__(256) void k_gemm2(const __half* __restrict__ O1,
                                               const float* __restrict__ W2,
                                               const float* __restrict__ sum1,
                                               const float* __restrict__ sq1,
                                               const float* __restrict__ g1,
                                               const float* __restrict__ be1,
                                               __half* __restrict__ H2) {
  __shared__ float xs[64 * 132];
  __shared__ float a1s[128], c1s[128];
  int tid = threadIdx.x;
  if (tid < 128) {
    float mu = sum1[tid] * (1.0f / NN);
    float var = sq1[tid] * (1.0f / NN) - mu * mu;
    float a = g1[tid] * rsqrtf(var + EPSB);
    a1s[tid] = a;
    c1s[tid] = be1[tid] - mu * a;
  }
  __syncthreads();
  int row0 = blockIdx.x * 64;
  for (int i = tid; i < 64 * 16; i += 256) {
    int r = i >> 4, k8 = i & 15;
    H8 t;
    if (row0 + r < NN)
      t.u = ((const uint4*)O1)[(size_t)(row0 + r) * 16 + k8];
    else
      t.u = make_uint4(0, 0, 0, 0);
#pragma unroll
    for (int jj = 0; jj < 4; ++jj) {
      float2 v = __half22float2(t.h[jj]);
      int fb = k8 * 8 + jj * 2;
      float y0 = fmaf(a1s[fb], v.x, c1s[fb]);
      float y1 = fmaf(a1s[fb + 1], v.y, c1s[fb + 1]);
      y0 = y0 >= 0.f ? y0 : SLOPE * y0;
      y1 = y1 >= 0.f ? y1 : SLOPE * y1;
      xs[r * 132 + fb] = y0;
      xs[r * 132 + fb + 1] = y1;
    }
  }
  __syncthreads();
  int cg = tid & 7, rg = tid >> 3;
  int f0 = cg * 8, r0 = rg * 2;
  float acc[2][8];
#pragma unroll
  for (int a = 0; a < 2; ++a)
#pragma unroll
    for (int b = 0; b < 8; ++b) acc[a][b] = 0.f;
  const float4* W4 = (const float4*)W2;
#pragma unroll 4
  for (int k = 0; k < 128; ++k) {
    float4 w0 = W4[k * 16 + (f0 >> 2)];
    float4 w1 = W4[k * 16 + (f0 >> 2) + 1];
    float wv[8] = {w0.x, w0.y, w0.z, w0.w, w1.x, w1.y, w1.z, w1.w};
    float x0 = xs[(r0 + 0) * 132 + k];
    float x1 = xs[(r0 + 1) * 132 + k];
#pragma unroll
    for (int b = 0; b < 8; ++b) {
      acc[0][b] += x0 * wv[b];
      acc[1][b] += x1 * wv[b];
    }
  }
#pragma unroll
  for (int a = 0; a < 2; ++a) {
    int r = row0 + r0 + a;
    if (r < NN) {
      H8 t;
      t.h[0] = __floats2half2_rn(acc[a][0], acc[a][1]);
      t.h[1] = __floats2half2_rn(acc[a][2], acc[a][3]);
      t.h[2] = __floats2half2_rn(acc[a][4], acc[a][5]);
      t.h[3] = __floats2half2_rn(acc[a][6], acc[a][7]);
      *(uint4*)&H2[(size_t)r * 64 + f0] = t.u;
    }
  }
}

// pull-gather layer2: fp16 rows, 16 lanes x 4 halves per node, fp32 out
__global__ __launch_bounds__(256) void k_gather2(const int* __restrict__ off,
                                                 const unsigned* __restrict__ sedge,
                                                 const float* __restrict__ dis,
                                                 const __half* __restrict__ H,
                                                 const float* __restrict__ b2,
                                                 float* __restrict__ O) {
  int node = blockIdx.x * 16 + (threadIdx.x >> 4);
  int f4 = threadIdx.x & 15;
  const uint2* Hh = (const uint2*)H;
  float4 acc = ((const float4*)b2)[f4];
  float dc = dis[node];
  int j0 = off[node], j1 = off[node + 1];
  int j = j0;
  for (; j + 1 < j1; j += 2) {
    unsigned u0 = sedge[j], u1 = sedge[j + 1];
    unsigned s0 = u0 >> 16, s1 = u1 >> 16;
    uint2 r0 = Hh[(size_t)s0 * 16 + f4];
    uint2 r1 = Hh[(size_t)s1 * 16 + f4];
    float n0 = dis[s0] * __half2float(__ushort_as_half((unsigned short)(u0 & 0xFFFFu))) * dc;
    float n1 = dis[s1] * __half2float(__ushort_as_half((unsigned short)(u1 & 0xFFFFu))) * dc;
    float2 a0 = __half22float2(*(__half2*)&r0.x);
    float2 b0 = __half22float2(*(__half2*)&r0.y);
    float2 a1 = __half22float2(*(__half2*)&r1.x);
    float2 b1v = __half22float2(*(__half2*)&r1.y);
    acc.x = fmaf(a0.x, n0, acc.x);
    acc.y = fmaf(a0.y, n0, acc.y);
    acc.z = fmaf(b0.x, n0, acc.z);
    acc.w = fmaf(b0.y, n0, acc.w);
    acc.x = fmaf(a1.x, n1, acc.x);
    acc.y = fmaf(a1.y, n1, acc.y);
    acc.z = fmaf(b1v.x, n1, acc.z);
    acc.w = fmaf(b1v.y, n1, acc.w);
  }
  if (j < j1) {
    unsigned u = sedge[j];
    unsigned s = u >> 16;
    uint2 r = Hh[(size_t)s * 16 + f4];
    float nm = dis[s] * __half2float(__ushort_as_half((unsigned short)(u & 0xFFFFu))) * dc;
    float2 a = __half22float2(*(__half2*)&r.x);
    float2 b = __half22float2(*(__half2*)&r.y);
    acc.x = fmaf(a.x, nm, acc.x);
    acc.y = fmaf(a.y, nm, acc.y);
    acc.z = fmaf(b.x, nm, acc.z);
    acc.w = fmaf(b.y, nm, acc.w);
  }
  ((float4*)O)[(size_t)node * 16 + f4] = acc;
}

__global__ void k_final(float* __restrict__ O, const float* __restrict__ sum2,
                        const float* __restrict__ sq2, const float* __restrict__ g2,
                        const float* __restrict__ be2) {
  int i = blockIdx.x * 256 + threadIdx.x;
  if (i < NN * 64) {
    int f = i & 63;
    float mu = sum2[f] * (1.0f / NN);
    float var = sq2[f] * (1.0f / NN) - mu * mu;
    float a = g2[f] * rsqrtf(var + EPSB);
    float c = be2[f] - mu * a;
    O[i] = fmaf(a, O[i], c);
  }
}

extern "C" void kernel_launch(void* const* d_in, const int* in_sizes, int n_in,
                              void* d_out, int out_size, void* d_ws, size_t ws_size,
                              hipStream_t stream) {
  const int* adj = (const int*)d_in[0];
  const float* w = (const float*)d_in[1];
  const float* X = (const float*)d_in[2];
  const float* W1 = (const float*)d_in[3];
  const float* b1 = (const float*)d_in[4];
  const float* g1 = (const float*)d_in[5];
  const float* be1 = (const float*)d_in[6];
  const float* W2 = (const float*)d_in[7];
  const float* b2 = (const float*)d_in[8];
  const float* g2 = (const float*)d_in[9];
  const float* be2 = (const float*)d_in[10];
  float* ws = (float*)d_ws;
  float* out = (float*)d_out;

  unsigned* sedge = (unsigned*)(ws + W_SEDGE);
  int* off = (int*)(ws + W_OFF);
  int* tb = (int*)(ws + W_TB);
  float* dis = ws + W_DIS;
  float* sum1 = ws + W_SUM1;
  float* sq1 = ws + W_SQ1;
  float* sum2 = ws + W_SUM2;
  float* sq2 = ws + W_SQ2;
  int* hist = (int*)(ws + W_HIST);
  int2* temp = (int2*)(ws + W_TEMP);
  __half* H1h = (__half*)(ws + W_H1);
  __half* H2h = (__half*)(ws + W_H1);  // aliases H1 (dead after gather1)
  __half* O1h = (__half*)(ws + W_O1);

  // zero BN stats only (everything else fully written before read)
  hipMemsetAsync(sum1, 0, (size_t)(W_SQ2 + 64 - W_SUM1) * sizeof(float), stream);

  k_countA<<<CB, 256, 0, stream>>>(adj + NE, hist);
  k_scanH<<<1, 1024, 0, stream>>>(hist, tb, off);
  k_scatC<<<CB, 256, 0, stream>>>(adj, w, hist, temp);
  k_binD<<<NBKT, 256, 0, stream>>>(temp, tb, dis, off, sedge);

  k_gemm1<<<(NN + 63) / 64, 256, 0, stream>>>(X, W1, H1h);
  k_gather1<<<NN / 8, 256, 0, stream>>>(off, sedge, dis, H1h, b1, O1h);
  k_statsh<<<512, 256, 0, stream>>>(O1h, sum1, sq1);

  k_gemm2<<<(NN + 63) / 64, 256, 0, stream>>>(O1h, W2, sum1, sq1, g1, be1, H2h);
  k_gather2<<<NN / 16, 256, 0, stream>>>(off, sedge, dis, H2h, b2, out);
  k_stats<<<512, 256, 0, stream>>>(out, sum2, sq2, 64);
  k_final<<<NN * 64 / 256, 256, 0, stream>>>(out, sum2, sq2, g2, be2);
}

// Round 10
// 307.550 us; speedup vs baseline: 7.4626x; 1.1234x over previous
//
#include <hip/hip_runtime.h>
#include <hip/hip_fp16.h>

#define NN 50000
#define NE 800000
#define NBKT 782          // ceil(NN/64) coarse buckets of 64 dests
#define CB 128            // count/scatter blocks
#define EPSB 1e-5f
#define SLOPE 0.01f
#define BCAP 2112         // LDS out-buffer cap per bucket (avg 1023+64)

// workspace layout (4-byte element offsets)
#define W_SEDGE 0          // NE+NN u32 = 850,000
#define W_OFF   850000     // NN+1 ints
#define W_TB    900004     // NBKT+1 ints
#define W_DIS   900800     // NN floats
#define W_SUM1  950800     // 128
#define W_SQ1   950928     // 128
#define W_SUM2  951056     // 64
#define W_SQ2   951120     // 64
#define W_HIST  951296     // CB*NBKT = 100,096 ints (block-major)
#define W_TEMP  1051392    // NE int2 = 1,600,000 ints (8B aligned)
#define W_H1    2651392    // N*128 fp16 = 3.2M float slots (H2 aliases)
#define W_O1    5851392    // N*128 fp16 = 3.2M float slots

union H8 { uint4 u; __half2 h[4]; };
typedef _Float16 f16x8 __attribute__((ext_vector_type(8)));
typedef float f32x4 __attribute__((ext_vector_type(4)));

// ---------------- preprocessing (unchanged from R8) ----------------

__global__ __launch_bounds__(256) void k_countA(const int* __restrict__ col,
                                                int* __restrict__ hist) {
  __shared__ int h[NBKT];
  for (int i = threadIdx.x; i < NBKT; i += 256) h[i] = 0;
  __syncthreads();
  const int per = (NE + CB - 1) / CB;
  int lo = blockIdx.x * per, hi = min(lo + per, NE);
  for (int e = lo + threadIdx.x; e < hi; e += 256)
    atomicAdd(&h[col[e] >> 6], 1);
  __syncthreads();
  for (int i = threadIdx.x; i < NBKT; i += 256)
    hist[blockIdx.x * NBKT + i] = h[i];
}

__global__ __launch_bounds__(1024) void k_scanH(int* __restrict__ hist,
                                                int* __restrict__ tb,
                                                int* __restrict__ off) {
  int t = threadIdx.x;
  int total = 0;
  if (t < NBKT)
    for (int i = 0; i < CB; ++i) total += hist[i * NBKT + t];
  __shared__ int ls[1024];
  ls[t] = (t < NBKT) ? total : 0;
  __syncthreads();
  for (int o = 1; o < 1024; o <<= 1) {
    int v = (t >= o) ? ls[t - o] : 0;
    __syncthreads();
    ls[t] += v;
    __syncthreads();
  }
  if (t < NBKT) {
    int run = ls[t] - total;
    tb[t] = run;
    for (int i = 0; i < CB; ++i) {
      int c = hist[i * NBKT + t];
      hist[i * NBKT + t] = run;
      run += c;
    }
  }
  if (t == 0) { tb[NBKT] = NE; off[NN] = NE + NN; }
}

__global__ __launch_bounds__(256) void k_scatC(const int* __restrict__ adj,
                                               const float* __restrict__ w,
                                               const int* __restrict__ hist,
                                               int2* __restrict__ temp) {
  __shared__ int cur[NBKT];
  for (int i = threadIdx.x; i < NBKT; i += 256)
    cur[i] = hist[blockIdx.x * NBKT + i];
  __syncthreads();
  const int per = (NE + CB - 1) / CB;
  int lo = blockIdx.x * per, hi = min(lo + per, NE);
  for (int e = lo + threadIdx.x; e < hi; e += 256) {
    int r = adj[e], c = adj[NE + e];
    int slot = atomicAdd(&cur[c >> 6], 1);
    temp[slot] = make_int2((r << 6) | (c & 63), __float_as_int(w[e]));
  }
}

__global__ __launch_bounds__(256) void k_binD(const int2* __restrict__ temp,
                                              const int* __restrict__ tb,
                                              float* __restrict__ dis,
                                              int* __restrict__ off,
                                              unsigned* __restrict__ sedge) {
  int k = blockIdx.x;
  int tb0 = tb[k];
  int Tk = tb[k + 1] - tb0;
  int d0 = k << 6;
  int nd = min(64, NN - d0);
  int fbase = tb0 + d0;
  __shared__ int cnt[64];
  __shared__ float wsum[64];
  __shared__ int lpos[64];
  __shared__ unsigned ob[BCAP];
  if (threadIdx.x < 64) { cnt[threadIdx.x] = 0; wsum[threadIdx.x] = 0.f; }
  __syncthreads();
  for (int i = threadIdx.x; i < Tk; i += 256) {
    int2 e = temp[tb0 + i];
    int dl = e.x & 63;
    atomicAdd(&cnt[dl], 1);
    atomicAdd(&wsum[dl], __int_as_float(e.y));
  }
  __syncthreads();
  if (threadIdx.x < 64) {
    int lane = threadIdx.x;
    int c = (lane < nd) ? cnt[lane] + 1 : 0;
    int v = c;
#pragma unroll
    for (int o = 1; o < 64; o <<= 1) {
      int u = __shfl_up(v, o, 64);
      if (lane >= o) v += u;
    }
    int base = v - c;
    if (lane < nd) {
      dis[d0 + lane] = rsqrtf(wsum[lane] + 1.0f);
      off[d0 + lane] = fbase + base;
      ob[base] = ((unsigned)(d0 + lane) << 16) | 0x3C00u;  // self: fp16(1.0)
      lpos[lane] = base + 1;
    }
  }
  __syncthreads();
  for (int i = threadIdx.x; i < Tk; i += 256) {
    int2 e = temp[tb0 + i];
    int dl = e.x & 63;
    unsigned src = ((unsigned)e.x) >> 6;
    int slot = atomicAdd(&lpos[dl], 1);
    __half hw = __float2half(__int_as_float(e.y));
    if (slot < BCAP)
      ob[slot] = (src << 16) | (unsigned)__half_as_ushort(hw);
  }
  __syncthreads();
  int tot = min(Tk + nd, BCAP);
  for (int i = threadIdx.x; i < tot; i += 256)
    sedge[fbase + i] = ob[i];
}

// ---------------- MFMA GEMM1: H1(fp16) = X @ W1 ----------------
// 64-row tile; X fp32->fp16 into XOR-swizzled LDS; W1 transposed to wt[n][k].
// A frag (16x16x32): lane l: m=l&15, k=8*(l>>4)+i ; B: n=l&15, same k.
__global__ __launch_bounds__(256) void k_gemm1m(const float* __restrict__ X,
                                                const float* __restrict__ W1,
                                                __half* __restrict__ H) {
  __shared__ _Float16 xs[64 * 128];
  __shared__ _Float16 wt[128 * 128];
  char* xsb = (char*)xs;
  char* wtb = (char*)wt;
  int tid = threadIdx.x;
  int row0 = blockIdx.x * 64;
  for (int i = tid; i < 64 * 32; i += 256) {
    int r = i >> 5, c4 = i & 31;
    float4 v = (row0 + r < NN) ? ((const float4*)X)[(size_t)(row0 + r) * 32 + c4]
                               : make_float4(0.f, 0.f, 0.f, 0.f);
    union { _Float16 h[4]; uint2 u; } p;
    p.h[0] = (_Float16)v.x; p.h[1] = (_Float16)v.y;
    p.h[2] = (_Float16)v.z; p.h[3] = (_Float16)v.w;
    int byte = (r * 256 + c4 * 8) ^ ((r & 7) << 4);
    *(uint2*)(xsb + byte) = p.u;
  }
  for (int i = tid; i < 128 * 32; i += 256) {
    int k = i >> 5, n4 = i & 31;
    float4 v = ((const float4*)W1)[k * 32 + n4];
    float vv[4] = {v.x, v.y, v.z, v.w};
#pragma unroll
    for (int j = 0; j < 4; ++j) {
      int n = n4 * 4 + j;
      int byte = (n * 256 + k * 2) ^ ((n & 7) << 4);
      *(_Float16*)(wtb + byte) = (_Float16)vv[j];
    }
  }
  __syncthreads();
  int l = tid & 63, w = tid >> 6;
  int lr = l & 15, lk2 = ((l >> 4) << 3) * 2;  // k byte offset within 64B
  f32x4 acc[8];
#pragma unroll
  for (int nt = 0; nt < 8; ++nt) acc[nt] = (f32x4){0.f, 0.f, 0.f, 0.f};
  int arow = w * 16 + lr;
  int asw = (arow & 7) << 4;
  int nsw = (lr & 7) << 4;
#pragma unroll
  for (int ks = 0; ks < 4; ++ks) {
    int kb = ks * 64 + lk2;
    f16x8 a = *(const f16x8*)(xsb + arow * 256 + (kb ^ asw));
#pragma unroll
    for (int nt = 0; nt < 8; ++nt) {
      int n = nt * 16 + lr;
      f16x8 b = *(const f16x8*)(wtb + n * 256 + (kb ^ nsw));
      acc[nt] = __builtin_amdgcn_mfma_f32_16x16x32_f16(a, b, acc[nt], 0, 0, 0);
    }
  }
  int orow = row0 + w * 16 + ((l >> 4) << 2);
#pragma unroll
  for (int r = 0; r < 4; ++r) {
    if (orow + r < NN) {
      __half* Hp = &H[(size_t)(orow + r) * 128 + lr];
#pragma unroll
      for (int nt = 0; nt < 8; ++nt)
        Hp[nt * 16] = __float2half(acc[nt][r]);
    }
  }
}

// ---------------- gather layer1 (unchanged) ----------------
__global__ __launch_bounds__(256) void k_gather1(const int* __restrict__ off,
                                                 const unsigned* __restrict__ sedge,
                                                 const float* __restrict__ dis,
                                                 const __half* __restrict__ H,
                                                 const float* __restrict__ b1,
                                                 __half* __restrict__ O) {
  int node = blockIdx.x * 8 + (threadIdx.x >> 5);
  int f4 = threadIdx.x & 31;
  const uint2* Hh = (const uint2*)H;
  float4 acc = ((const float4*)b1)[f4];
  float dc = dis[node];
  int j0 = off[node], j1 = off[node + 1];
  int j = j0;
  for (; j + 1 < j1; j += 2) {
    unsigned u0 = sedge[j], u1 = sedge[j + 1];
    unsigned s0 = u0 >> 16, s1 = u1 >> 16;
    uint2 r0 = Hh[(size_t)s0 * 32 + f4];
    uint2 r1 = Hh[(size_t)s1 * 32 + f4];
    float n0 = dis[s0] * __half2float(__ushort_as_half((unsigned short)(u0 & 0xFFFFu))) * dc;
    float n1 = dis[s1] * __half2float(__ushort_as_half((unsigned short)(u1 & 0xFFFFu))) * dc;
    float2 a0 = __half22float2(*(__half2*)&r0.x);
    float2 b0 = __half22float2(*(__half2*)&r0.y);
    float2 a1 = __half22float2(*(__half2*)&r1.x);
    float2 b1v = __half22float2(*(__half2*)&r1.y);
    acc.x = fmaf(a0.x, n0, acc.x);
    acc.y = fmaf(a0.y, n0, acc.y);
    acc.z = fmaf(b0.x, n0, acc.z);
    acc.w = fmaf(b0.y, n0, acc.w);
    acc.x = fmaf(a1.x, n1, acc.x);
    acc.y = fmaf(a1.y, n1, acc.y);
    acc.z = fmaf(b1v.x, n1, acc.z);
    acc.w = fmaf(b1v.y, n1, acc.w);
  }
  if (j < j1) {
    unsigned u = sedge[j];
    unsigned s = u >> 16;
    uint2 r = Hh[(size_t)s * 32 + f4];
    float nm = dis[s] * __half2float(__ushort_as_half((unsigned short)(u & 0xFFFFu))) * dc;
    float2 a = __half22float2(*(__half2*)&r.x);
    float2 b = __half22float2(*(__half2*)&r.y);
    acc.x = fmaf(a.x, nm, acc.x);
    acc.y = fmaf(a.y, nm, acc.y);
    acc.z = fmaf(b.x, nm, acc.z);
    acc.w = fmaf(b.y, nm, acc.w);
  }
  uint2 o;
  *(__half2*)&o.x = __floats2half2_rn(acc.x, acc.y);
  *(__half2*)&o.y = __floats2half2_rn(acc.z, acc.w);
  ((uint2*)O)[(size_t)node * 32 + f4] = o;
}

__global__ __launch_bounds__(256) void k_statsh(const __half* __restrict__ X,
                                                float* __restrict__ sum,
                                                float* __restrict__ sq) {
  int f2 = threadIdx.x & 63;
  int rg = threadIdx.x >> 6;
  float sx = 0.f, sy = 0.f, ssx = 0.f, ssy = 0.f;
  const unsigned* X2 = (const unsigned*)X;
  for (int r = blockIdx.x * 4 + rg; r < NN; r += gridDim.x * 4) {
    unsigned u = X2[(size_t)r * 64 + f2];
    float2 v = __half22float2(*(__half2*)&u);
    sx += v.x; sy += v.y;
    ssx += v.x * v.x; ssy += v.y * v.y;
  }
  __shared__ float ls[256][4];
  ls[threadIdx.x][0] = sx; ls[threadIdx.x][1] = sy;
  ls[threadIdx.x][2] = ssx; ls[threadIdx.x][3] = ssy;
  __syncthreads();
  if (rg == 0) {
    for (int g = 1; g < 4; ++g) {
      sx += ls[g * 64 + f2][0]; sy += ls[g * 64 + f2][1];
      ssx += ls[g * 64 + f2][2]; ssy += ls[g * 64 + f2][3];
    }
    atomicAdd(&sum[2 * f2], sx);
    atomicAdd(&sum[2 * f2 + 1], sy);
    atomicAdd(&sq[2 * f2], ssx);
    atomicAdd(&sq[2 * f2 + 1], ssy);
  }
}

__global__ void k_stats(const float* __restrict__ X, float* __restrict__ sum,
                        float* __restrict__ sq, int C) {
  int f = threadIdx.x & (C - 1);
  int rg = threadIdx.x / C;
  int nrg = 256 / C;
  float s = 0.f, ss = 0.f;
  for (int r = blockIdx.x * nrg + rg; r < NN; r += gridDim.x * nrg) {
    float v = X[(size_t)r * C + f];
    s += v;
    ss += v * v;
  }
  __shared__ float ls[256], lss[256];
  ls[threadIdx.x] = s;
  lss[threadIdx.x] = ss;
  __syncthreads();
  if (rg == 0) {
    for (int g = 1; g < nrg; ++g) { s += ls[g * C + f]; ss += lss[g * C + f]; }
    atomicAdd(&sum[f], s);
    atomicAdd(&sq[f], ss);
  }
}

// ---------------- MFMA GEMM2: H2(fp16) = leaky(BN1(O1)) @ W2 ----------------
__global__ __launch_bounds__(256) void k_gemm2m(const __half* __restrict__ O1,
                                                const float* __restrict__ W2,
                                                const float* __restrict__ sum1,
                                                const float* __restrict__ sq1,
                                                const float* __restrict__ g1,
                                                const float* __restrict__ be1,
                                                __half* __restrict__ H2) {
  __shared__ _Float16 xs[64 * 128];
  __shared__ _Float16 wt[64 * 128];
  __shared__ float a1s[128], c1s[128];
  char* xsb = (char*)xs;
  char* wtb = (char*)wt;
  int tid = threadIdx.x;
  if (tid < 128) {
    float mu = sum1[tid] * (1.0f / NN);
    float var = sq1[tid] * (1.0f / NN) - mu * mu;
    float a = g1[tid] * rsqrtf(var + EPSB);
    a1s[tid] = a;
    c1s[tid] = be1[tid] - mu * a;
  }
  __syncthreads();
  int row0 = blockIdx.x * 64;
  for (int i = tid; i < 64 * 16; i += 256) {
    int r = i >> 4, k8 = i & 15;
    H8 t;
    t.u = (row0 + r < NN) ? ((const uint4*)O1)[(size_t)(row0 + r) * 16 + k8]
                          : make_uint4(0, 0, 0, 0);
    union { _Float16 h[8]; uint4 u; } p;
#pragma unroll
    for (int jj = 0; jj < 4; ++jj) {
      float2 v = __half22float2(t.h[jj]);
      int fb = k8 * 8 + jj * 2;
      float y0 = fmaf(a1s[fb], v.x, c1s[fb]);
      float y1 = fmaf(a1s[fb + 1], v.y, c1s[fb + 1]);
      y0 = y0 >= 0.f ? y0 : SLOPE * y0;
      y1 = y1 >= 0.f ? y1 : SLOPE * y1;
      p.h[jj * 2] = (_Float16)y0;
      p.h[jj * 2 + 1] = (_Float16)y1;
    }
    int byte = (r * 256 + k8 * 16) ^ ((r & 7) << 4);
    *(uint4*)(xsb + byte) = p.u;
  }
  for (int i = tid; i < 128 * 16; i += 256) {
    int k = i >> 4, n4 = i & 15;
    float4 v = ((const float4*)W2)[k * 16 + n4];
    float vv[4] = {v.x, v.y, v.z, v.w};
#pragma unroll
    for (int j = 0; j < 4; ++j) {
      int n = n4 * 4 + j;
      int byte = (n * 256 + k * 2) ^ ((n & 7) << 4);
      *(_Float16*)(wtb + byte) = (_Float16)vv[j];
    }
  }
  __syncthreads();
  int l = tid & 63, w = tid >> 6;
  int lr = l & 15, lk2 = ((l >> 4) << 3) * 2;
  f32x4 acc[4];
#pragma unroll
  for (int nt = 0; nt < 4; ++nt) acc[nt] = (f32x4){0.f, 0.f, 0.f, 0.f};
  int arow = w * 16 + lr;
  int asw = (arow & 7) << 4;
  int nsw = (lr & 7) << 4;
#pragma unroll
  for (int ks = 0; ks < 4; ++ks) {
    int kb = ks * 64 + lk2;
    f16x8 a = *(const f16x8*)(xsb + arow * 256 + (kb ^ asw));
#pragma unroll
    for (int nt = 0; nt < 4; ++nt) {
      int n = nt * 16 + lr;
      f16x8 b = *(const f16x8*)(wtb + n * 256 + (kb ^ nsw));
      acc[nt] = __builtin_amdgcn_mfma_f32_16x16x32_f16(a, b, acc[nt], 0, 0, 0);
    }
  }
  int orow = row0 + w * 16 + ((l >> 4) << 2);
#pragma unroll
  for (int r = 0; r < 4; ++r) {
    if (orow + r < NN) {
      __half* Hp = &H2[(size_t)(orow + r) * 64 + lr];
#pragma unroll
      for (int nt = 0; nt < 4; ++nt)
        Hp[nt * 16] = __float2half(acc[nt][r]);
    }
  }
}

// ---------------- gather layer2 + BN2 finish (unchanged) ----------------
__global__ __launch_bounds__(256) void k_gather2(const int* __restrict__ off,
                                                 const unsigned* __restrict__ sedge,
                                                 const float* __restrict__ dis,
                                                 const __half* __restrict__ H,
                                                 const float* __restrict__ b2,
                                                 float* __restrict__ O) {
  int node = blockIdx.x * 16 + (threadIdx.x >> 4);
  int f4 = threadIdx.x & 15;
  const uint2* Hh = (const uint2*)H;
  float4 acc = ((const float4*)b2)[f4];
  float dc = dis[node];
  int j0 = off[node], j1 = off[node + 1];
  int j = j0;
  for (; j + 1 < j1; j += 2) {
    unsigned u0 = sedge[j], u1 = sedge[j + 1];
    unsigned s0 = u0 >> 16, s1 = u1 >> 16;
    uint2 r0 = Hh[(size_t)s0 * 16 + f4];
    uint2 r1 = Hh[(size_t)s1 * 16 + f4];
    float n0 = dis[s0] * __half2float(__ushort_as_half((unsigned short)(u0 & 0xFFFFu))) * dc;
    float n1 = dis[s1] * __half2float(__ushort_as_half((unsigned short)(u1 & 0xFFFFu))) * dc;
    float2 a0 = __half22float2(*(__half2*)&r0.x);
    float2 b0 = __half22float2(*(__half2*)&r0.y);
    float2 a1 = __half22float2(*(__half2*)&r1.x);
    float2 b1v = __half22float2(*(__half2*)&r1.y);
    acc.x = fmaf(a0.x, n0, acc.x);
    acc.y = fmaf(a0.y, n0, acc.y);
    acc.z = fmaf(b0.x, n0, acc.z);
    acc.w = fmaf(b0.y, n0, acc.w);
    acc.x = fmaf(a1.x, n1, acc.x);
    acc.y = fmaf(a1.y, n1, acc.y);
    acc.z = fmaf(b1v.x, n1, acc.z);
    acc.w = fmaf(b1v.y, n1, acc.w);
  }
  if (j < j1) {
    unsigned u = sedge[j];
    unsigned s = u >> 16;
    uint2 r = Hh[(size_t)s * 16 + f4];
    float nm = dis[s] * __half2float(__ushort_as_half((unsigned short)(u & 0xFFFFu))) * dc;
    float2 a = __half22float2(*(__half2*)&r.x);
    float2 b = __half22float2(*(__half2*)&r.y);
    acc.x = fmaf(a.x, nm, acc.x);
    acc.y = fmaf(a.y, nm, acc.y);
    acc.z = fmaf(b.x, nm, acc.z);
    acc.w = fmaf(b.y, nm, acc.w);
  }
  ((float4*)O)[(size_t)node * 16 + f4] = acc;
}

__global__ void k_final(float* __restrict__ O, const float* __restrict__ sum2,
                        const float* __restrict__ sq2, const float* __restrict__ g2,
                        const float* __restrict__ be2) {
  int i = blockIdx.x * 256 + threadIdx.x;
  if (i < NN * 64) {
    int f = i & 63;
    float mu = sum2[f] * (1.0f / NN);
    float var = sq2[f] * (1.0f / NN) - mu * mu;
    float a = g2[f] * rsqrtf(var + EPSB);
    float c = be2[f] - mu * a;
    O[i] = fmaf(a, O[i], c);
  }
}

extern "C" void kernel_launch(void* const* d_in, const int* in_sizes, int n_in,
                              void* d_out, int out_size, void* d_ws, size_t ws_size,
                              hipStream_t stream) {
  const int* adj = (const int*)d_in[0];
  const float* w = (const float*)d_in[1];
  const float* X = (const float*)d_in[2];
  const float* W1 = (const float*)d_in[3];
  const float* b1 = (const float*)d_in[4];
  const float* g1 = (const float*)d_in[5];
  const float* be1 = (const float*)d_in[6];
  const float* W2 = (const float*)d_in[7];
  const float* b2 = (const float*)d_in[8];
  const float* g2 = (const float*)d_in[9];
  const float* be2 = (const float*)d_in[10];
  float* ws = (float*)d_ws;
  float* out = (float*)d_out;

  unsigned* sedge = (unsigned*)(ws + W_SEDGE);
  int* off = (int*)(ws + W_OFF);
  int* tb = (int*)(ws + W_TB);
  float* dis = ws + W_DIS;
  float* sum1 = ws + W_SUM1;
  float* sq1 = ws + W_SQ1;
  float* sum2 = ws + W_SUM2;
  float* sq2 = ws + W_SQ2;
  int* hist = (int*)(ws + W_HIST);
  int2* temp = (int2*)(ws + W_TEMP);
  __half* H1h = (__half*)(ws + W_H1);
  __half* H2h = (__half*)(ws + W_H1);  // aliases H1 (dead after gather1)
  __half* O1h = (__half*)(ws + W_O1);

  hipMemsetAsync(sum1, 0, (size_t)(W_SQ2 + 64 - W_SUM1) * sizeof(float), stream);

  k_countA<<<CB, 256, 0, stream>>>(adj + NE, hist);
  k_scanH<<<1, 1024, 0, stream>>>(hist, tb, off);
  k_scatC<<<CB, 256, 0, stream>>>(adj, w, hist, temp);
  k_binD<<<NBKT, 256, 0, stream>>>(temp, tb, dis, off, sedge);

  k_gemm1m<<<(NN + 63) / 64, 256, 0, stream>>>(X, W1, H1h);
  k_gather1<<<NN / 8, 256, 0, stream>>>(off, sedge, dis, H1h, b1, O1h);
  k_statsh<<<512, 256, 0, stream>>>(O1h, sum1, sq1);

  k_gemm2m<<<(NN + 63) / 64, 256, 0, stream>>>(O1h, W2, sum1, sq1, g1, be1, H2h);
  k_gather2<<<NN / 16, 256, 0, stream>>>(off, sedge, dis, H2h, b2, out);
  k_stats<<<512, 256, 0, stream>>>(out, sum2, sq2, 64);
  k_final<<<NN * 64 / 256, 256, 0, stream>>>(out, sum2, sq2, g2, be2);
}

// Round 11
// 271.579 us; speedup vs baseline: 8.4510x; 1.1325x over previous
//
#include <hip/hip_runtime.h>
#include <hip/hip_fp16.h>

#define NN 50000
#define NE 800000
#define NBKT 782          // ceil(NN/64) coarse buckets of 64 dests
#define CB 128            // scatter blocks
#define ECAP 1280         // fixed temp capacity per bucket (mean 1024, +8 sigma)
#define SCAP 1344         // sedge capacity per bucket (ECAP + 64 self slots)
#define EPSB 1e-5f
#define SLOPE 0.01f

// workspace layout (4-byte element offsets)
#define W_SEDGE 0          // NBKT*SCAP u32 = 1,051,008
#define W_OFFS  1051008    // NN ints
#define W_OFFE  1101008    // NN ints
#define W_DIS   1151008    // NN floats
#define W_CNTG  1201008    // NBKT ints (zeroed)
#define W_SUM1  1201792    // 128 (zeroed)
#define W_SQ1   1201920    // 128
#define W_SUM2  1202048    // 64
#define W_SQ2   1202112    // 64
#define W_TEMP  1202176    // NBKT*ECAP int2 = 2,001,920 ints (8B aligned: even)
#define W_H1    3204096    // N*128 fp16 = 3.2M float slots (H2 aliases)
#define W_O1    6404096    // N*128 fp16 = 3.2M float slots

union H8 { uint4 u; __half2 h[4]; };
typedef _Float16 f16x8 __attribute__((ext_vector_type(8)));
typedef float f32x4 __attribute__((ext_vector_type(4)));

// scatter with self-reserved bucket ranges: LDS count pass -> one global
// atomicAdd per (block,bucket) -> scatter into fixed per-bucket region.
__global__ __launch_bounds__(256) void k_scatC2(const int* __restrict__ adj,
                                                const float* __restrict__ w,
                                                int* __restrict__ cnt_g,
                                                int2* __restrict__ temp) {
  __shared__ int h[NBKT];
  __shared__ int cur[NBKT];
  for (int i = threadIdx.x; i < NBKT; i += 256) h[i] = 0;
  __syncthreads();
  const int per = (NE + CB - 1) / CB;
  int lo = blockIdx.x * per, hi = min(lo + per, NE);
  for (int e = lo + threadIdx.x; e < hi; e += 256)
    atomicAdd(&h[adj[NE + e] >> 6], 1);
  __syncthreads();
  for (int i = threadIdx.x; i < NBKT; i += 256) {
    int c = h[i];
    int base = c ? atomicAdd(&cnt_g[i], c) : 0;
    cur[i] = i * ECAP + base;
  }
  __syncthreads();
  for (int e = lo + threadIdx.x; e < hi; e += 256) {
    int r = adj[e], c = adj[NE + e];
    int b = c >> 6;
    int slot = atomicAdd(&cur[b], 1);
    if (slot < (b + 1) * ECAP)   // overflow guard (astronomically unlikely)
      temp[slot] = make_int2((r << 6) | (c & 63), __float_as_int(w[e]));
  }
}

// per-bucket: LDS count+wsum (degree), dis=rsqrt, wave scan for per-dest
// ranges, group edges with self edge in slot 0, coalesced write-out.
// No global prefix needed: each bucket owns sedge[k*SCAP ...].
__global__ __launch_bounds__(256) void k_binD2(const int2* __restrict__ temp,
                                               const int* __restrict__ cnt_g,
                                               float* __restrict__ dis,
                                               int* __restrict__ offS,
                                               int* __restrict__ offE,
                                               unsigned* __restrict__ sedge) {
  int k = blockIdx.x;
  int Tk = min(cnt_g[k], ECAP);
  int d0 = k << 6;
  int nd = min(64, NN - d0);
  int fbase = k * SCAP;
  const int2* tb = temp + (size_t)k * ECAP;
  __shared__ int cnt[64];
  __shared__ float wsum[64];
  __shared__ int lpos[64];
  __shared__ unsigned ob[SCAP];
  if (threadIdx.x < 64) { cnt[threadIdx.x] = 0; wsum[threadIdx.x] = 0.f; }
  __syncthreads();
  for (int i = threadIdx.x; i < Tk; i += 256) {
    int2 e = tb[i];
    int dl = e.x & 63;
    atomicAdd(&cnt[dl], 1);
    atomicAdd(&wsum[dl], __int_as_float(e.y));
  }
  __syncthreads();
  if (threadIdx.x < 64) {  // wave 0: exclusive scan of cnt+1
    int lane = threadIdx.x;
    int c = (lane < nd) ? cnt[lane] + 1 : 0;
    int v = c;
#pragma unroll
    for (int o = 1; o < 64; o <<= 1) {
      int u = __shfl_up(v, o, 64);
      if (lane >= o) v += u;
    }
    int base = v - c;
    if (lane < nd) {
      dis[d0 + lane] = rsqrtf(wsum[lane] + 1.0f);
      offS[d0 + lane] = fbase + base;
      offE[d0 + lane] = fbase + base + c;
      ob[base] = ((unsigned)(d0 + lane) << 16) | 0x3C00u;  // self: fp16(1.0)
      lpos[lane] = base + 1;
    }
  }
  __syncthreads();
  for (int i = threadIdx.x; i < Tk; i += 256) {
    int2 e = tb[i];
    int dl = e.x & 63;
    unsigned src = ((unsigned)e.x) >> 6;
    int slot = atomicAdd(&lpos[dl], 1);
    __half hw = __float2half(__int_as_float(e.y));
    ob[slot] = (src << 16) | (unsigned)__half_as_ushort(hw);
  }
  __syncthreads();
  int tot = Tk + nd;
  for (int i = threadIdx.x; i < tot; i += 256)
    sedge[fbase + i] = ob[i];
}

// ---------------- MFMA GEMM1: H1(fp16) = X @ W1 ----------------
__global__ __launch_bounds__(256) void k_gemm1m(const float* __restrict__ X,
                                                const float* __restrict__ W1,
                                                __half* __restrict__ H) {
  __shared__ _Float16 xs[64 * 128];
  __shared__ _Float16 wt[128 * 128];
  char* xsb = (char*)xs;
  char* wtb = (char*)wt;
  int tid = threadIdx.x;
  int row0 = blockIdx.x * 64;
  for (int i = tid; i < 64 * 32; i += 256) {
    int r = i >> 5, c4 = i & 31;
    float4 v = (row0 + r < NN) ? ((const float4*)X)[(size_t)(row0 + r) * 32 + c4]
                               : make_float4(0.f, 0.f, 0.f, 0.f);
    union { _Float16 h[4]; uint2 u; } p;
    p.h[0] = (_Float16)v.x; p.h[1] = (_Float16)v.y;
    p.h[2] = (_Float16)v.z; p.h[3] = (_Float16)v.w;
    int byte = (r * 256 + c4 * 8) ^ ((r & 7) << 4);
    *(uint2*)(xsb + byte) = p.u;
  }
  for (int i = tid; i < 128 * 32; i += 256) {
    int k = i >> 5, n4 = i & 31;
    float4 v = ((const float4*)W1)[k * 32 + n4];
    float vv[4] = {v.x, v.y, v.z, v.w};
#pragma unroll
    for (int j = 0; j < 4; ++j) {
      int n = n4 * 4 + j;
      int byte = (n * 256 + k * 2) ^ ((n & 7) << 4);
      *(_Float16*)(wtb + byte) = (_Float16)vv[j];
    }
  }
  __syncthreads();
  int l = tid & 63, w = tid >> 6;
  int lr = l & 15, lk2 = ((l >> 4) << 3) * 2;
  f32x4 acc[8];
#pragma unroll
  for (int nt = 0; nt < 8; ++nt) acc[nt] = (f32x4){0.f, 0.f, 0.f, 0.f};
  int arow = w * 16 + lr;
  int asw = (arow & 7) << 4;
  int nsw = (lr & 7) << 4;
#pragma unroll
  for (int ks = 0; ks < 4; ++ks) {
    int kb = ks * 64 + lk2;
    f16x8 a = *(const f16x8*)(xsb + arow * 256 + (kb ^ asw));
#pragma unroll
    for (int nt = 0; nt < 8; ++nt) {
      int n = nt * 16 + lr;
      f16x8 b = *(const f16x8*)(wtb + n * 256 + (kb ^ nsw));
      acc[nt] = __builtin_amdgcn_mfma_f32_16x16x32_f16(a, b, acc[nt], 0, 0, 0);
    }
  }
  int orow = row0 + w * 16 + ((l >> 4) << 2);
#pragma unroll
  for (int r = 0; r < 4; ++r) {
    if (orow + r < NN) {
      __half* Hp = &H[(size_t)(orow + r) * 128 + lr];
#pragma unroll
      for (int nt = 0; nt < 8; ++nt)
        Hp[nt * 16] = __float2half(acc[nt][r]);
    }
  }
}

// pull-gather layer1, unroll x4 for outstanding-load depth
__global__ __launch_bounds__(256) void k_gather1(const int* __restrict__ offS,
                                                 const int* __restrict__ offE,
                                                 const unsigned* __restrict__ sedge,
                                                 const float* __restrict__ dis,
                                                 const __half* __restrict__ H,
                                                 const float* __restrict__ b1,
                                                 __half* __restrict__ O) {
  int node = blockIdx.x * 8 + (threadIdx.x >> 5);
  int f4 = threadIdx.x & 31;
  const uint2* Hh = (const uint2*)H;
  float4 acc = ((const float4*)b1)[f4];
  float dc = dis[node];
  int j0 = offS[node], j1 = offE[node];
  int j = j0;
  for (; j + 3 < j1; j += 4) {
    unsigned u0 = sedge[j], u1 = sedge[j + 1];
    unsigned u2 = sedge[j + 2], u3 = sedge[j + 3];
    unsigned s0 = u0 >> 16, s1 = u1 >> 16, s2 = u2 >> 16, s3 = u3 >> 16;
    uint2 r0 = Hh[(size_t)s0 * 32 + f4];
    uint2 r1 = Hh[(size_t)s1 * 32 + f4];
    uint2 r2 = Hh[(size_t)s2 * 32 + f4];
    uint2 r3 = Hh[(size_t)s3 * 32 + f4];
    float n0 = dis[s0] * __half2float(__ushort_as_half((unsigned short)(u0 & 0xFFFFu))) * dc;
    float n1 = dis[s1] * __half2float(__ushort_as_half((unsigned short)(u1 & 0xFFFFu))) * dc;
    float n2 = dis[s2] * __half2float(__ushort_as_half((unsigned short)(u2 & 0xFFFFu))) * dc;
    float n3 = dis[s3] * __half2float(__ushort_as_half((unsigned short)(u3 & 0xFFFFu))) * dc;
    float2 a0 = __half22float2(*(__half2*)&r0.x);
    float2 c0 = __half22float2(*(__half2*)&r0.y);
    float2 a1 = __half22float2(*(__half2*)&r1.x);
    float2 c1 = __half22float2(*(__half2*)&r1.y);
    float2 a2 = __half22float2(*(__half2*)&r2.x);
    float2 c2 = __half22float2(*(__half2*)&r2.y);
    float2 a3 = __half22float2(*(__half2*)&r3.x);
    float2 c3 = __half22float2(*(__half2*)&r3.y);
    acc.x = fmaf(a0.x, n0, acc.x); acc.y = fmaf(a0.y, n0, acc.y);
    acc.z = fmaf(c0.x, n0, acc.z); acc.w = fmaf(c0.y, n0, acc.w);
    acc.x = fmaf(a1.x, n1, acc.x); acc.y = fmaf(a1.y, n1, acc.y);
    acc.z = fmaf(c1.x, n1, acc.z); acc.w = fmaf(c1.y, n1, acc.w);
    acc.x = fmaf(a2.x, n2, acc.x); acc.y = fmaf(a2.y, n2, acc.y);
    acc.z = fmaf(c2.x, n2, acc.z); acc.w = fmaf(c2.y, n2, acc.w);
    acc.x = fmaf(a3.x, n3, acc.x); acc.y = fmaf(a3.y, n3, acc.y);
    acc.z = fmaf(c3.x, n3, acc.z); acc.w = fmaf(c3.y, n3, acc.w);
  }
  for (; j < j1; ++j) {
    unsigned u = sedge[j];
    unsigned s = u >> 16;
    uint2 r = Hh[(size_t)s * 32 + f4];
    float nm = dis[s] * __half2float(__ushort_as_half((unsigned short)(u & 0xFFFFu))) * dc;
    float2 a = __half22float2(*(__half2*)&r.x);
    float2 b = __half22float2(*(__half2*)&r.y);
    acc.x = fmaf(a.x, nm, acc.x); acc.y = fmaf(a.y, nm, acc.y);
    acc.z = fmaf(b.x, nm, acc.z); acc.w = fmaf(b.y, nm, acc.w);
  }
  uint2 o;
  *(__half2*)&o.x = __floats2half2_rn(acc.x, acc.y);
  *(__half2*)&o.y = __floats2half2_rn(acc.z, acc.w);
  ((uint2*)O)[(size_t)node * 32 + f4] = o;
}

__global__ __launch_bounds__(256) void k_statsh(const __half* __restrict__ X,
                                                float* __restrict__ sum,
                                                float* __restrict__ sq) {
  int f2 = threadIdx.x & 63;
  int rg = threadIdx.x >> 6;
  float sx = 0.f, sy = 0.f, ssx = 0.f, ssy = 0.f;
  const unsigned* X2 = (const unsigned*)X;
  for (int r = blockIdx.x * 4 + rg; r < NN; r += gridDim.x * 4) {
    unsigned u = X2[(size_t)r * 64 + f2];
    float2 v = __half22float2(*(__half2*)&u);
    sx += v.x; sy += v.y;
    ssx += v.x * v.x; ssy += v.y * v.y;
  }
  __shared__ float ls[256][4];
  ls[threadIdx.x][0] = sx; ls[threadIdx.x][1] = sy;
  ls[threadIdx.x][2] = ssx; ls[threadIdx.x][3] = ssy;
  __syncthreads();
  if (rg == 0) {
    for (int g = 1; g < 4; ++g) {
      sx += ls[g * 64 + f2][0]; sy += ls[g * 64 + f2][1];
      ssx += ls[g * 64 + f2][2]; ssy += ls[g * 64 + f2][3];
    }
    atomicAdd(&sum[2 * f2], sx);
    atomicAdd(&sum[2 * f2 + 1], sy);
    atomicAdd(&sq[2 * f2], ssx);
    atomicAdd(&sq[2 * f2 + 1], ssy);
  }
}

__global__ void k_stats(const float* __restrict__ X, float* __restrict__ sum,
                        float* __restrict__ sq, int C) {
  int f = threadIdx.x & (C - 1);
  int rg = threadIdx.x / C;
  int nrg = 256 / C;
  float s = 0.f, ss = 0.f;
  for (int r = blockIdx.x * nrg + rg; r < NN; r += gridDim.x * nrg) {
    float v = X[(size_t)r * C + f];
    s += v;
    ss += v * v;
  }
  __shared__ float ls[256], lss[256];
  ls[threadIdx.x] = s;
  lss[threadIdx.x] = ss;
  __syncthreads();
  if (rg == 0) {
    for (int g = 1; g < nrg; ++g) { s += ls[g * C + f]; ss += lss[g * C + f]; }
    atomicAdd(&sum[f], s);
    atomicAdd(&sq[f], ss);
  }
}

// ---------------- MFMA GEMM2: H2(fp16) = leaky(BN1(O1)) @ W2 ----------------
__global__ __launch_bounds__(256) void k_gemm2m(const __half* __restrict__ O1,
                                                const float* __restrict__ W2,
                                                const float* __restrict__ sum1,
                                                const float* __restrict__ sq1,
                                                const float* __restrict__ g1,
                                                const float* __restrict__ be1,
                                                __half* __restrict__ H2) {
  __shared__ _Float16 xs[64 * 128];
  __shared__ _Float16 wt[64 * 128];
  __shared__ float a1s[128], c1s[128];
  char* xsb = (char*)xs;
  char* wtb = (char*)wt;
  int tid = threadIdx.x;
  if (tid < 128) {
    float mu = sum1[tid] * (1.0f / NN);
    float var = sq1[tid] * (1.0f / NN) - mu * mu;
    float a = g1[tid] * rsqrtf(var + EPSB);
    a1s[tid] = a;
    c1s[tid] = be1[tid] - mu * a;
  }
  __syncthreads();
  int row0 = blockIdx.x * 64;
  for (int i = tid; i < 64 * 16; i += 256) {
    int r = i >> 4, k8 = i & 15;
    H8 t;
    t.u = (row0 + r < NN) ? ((const uint4*)O1)[(size_t)(row0 + r) * 16 + k8]
                          : make_uint4(0, 0, 0, 0);
    union { _Float16 h[8]; uint4 u; } p;
#pragma unroll
    for (int jj = 0; jj < 4; ++jj) {
      float2 v = __half22float2(t.h[jj]);
      int fb = k8 * 8 + jj * 2;
      float y0 = fmaf(a1s[fb], v.x, c1s[fb]);
      float y1 = fmaf(a1s[fb + 1], v.y, c1s[fb + 1]);
      y0 = y0 >= 0.f ? y0 : SLOPE * y0;
      y1 = y1 >= 0.f ? y1 : SLOPE * y1;
      p.h[jj * 2] = (_Float16)y0;
      p.h[jj * 2 + 1] = (_Float16)y1;
    }
    int byte = (r * 256 + k8 * 16) ^ ((r & 7) << 4);
    *(uint4*)(xsb + byte) = p.u;
  }
  for (int i = tid; i < 128 * 16; i += 256) {
    int k = i >> 4, n4 = i & 15;
    float4 v = ((const float4*)W2)[k * 16 + n4];
    float vv[4] = {v.x, v.y, v.z, v.w};
#pragma unroll
    for (int j = 0; j < 4; ++j) {
      int n = n4 * 4 + j;
      int byte = (n * 256 + k * 2) ^ ((n & 7) << 4);
      *(_Float16*)(wtb + byte) = (_Float16)vv[j];
    }
  }
  __syncthreads();
  int l = tid & 63, w = tid >> 6;
  int lr = l & 15, lk2 = ((l >> 4) << 3) * 2;
  f32x4 acc[4];
#pragma unroll
  for (int nt = 0; nt < 4; ++nt) acc[nt] = (f32x4){0.f, 0.f, 0.f, 0.f};
  int arow = w * 16 + lr;
  int asw = (arow & 7) << 4;
  int nsw = (lr & 7) << 4;
#pragma unroll
  for (int ks = 0; ks < 4; ++ks) {
    int kb = ks * 64 + lk2;
    f16x8 a = *(const f16x8*)(xsb + arow * 256 + (kb ^ asw));
#pragma unroll
    for (int nt = 0; nt < 4; ++nt) {
      int n = nt * 16 + lr;
      f16x8 b = *(const f16x8*)(wtb + n * 256 + (kb ^ nsw));
      acc[nt] = __builtin_amdgcn_mfma_f32_16x16x32_f16(a, b, acc[nt], 0, 0, 0);
    }
  }
  int orow = row0 + w * 16 + ((l >> 4) << 2);
#pragma unroll
  for (int r = 0; r < 4; ++r) {
    if (orow + r < NN) {
      __half* Hp = &H2[(size_t)(orow + r) * 64 + lr];
#pragma unroll
      for (int nt = 0; nt < 4; ++nt)
        Hp[nt * 16] = __float2half(acc[nt][r]);
    }
  }
}

// pull-gather layer2, unroll x4
__global__ __launch_bounds__(256) void k_gather2(const int* __restrict__ offS,
                                                 const int* __restrict__ offE,
                                                 const unsigned* __restrict__ sedge,
                                                 const float* __restrict__ dis,
                                                 const __half* __restrict__ H,
                                                 const float* __restrict__ b2,
                                                 float* __restrict__ O) {
  int node = blockIdx.x * 16 + (threadIdx.x >> 4);
  int f4 = threadIdx.x & 15;
  const uint2* Hh = (const uint2*)H;
  float4 acc = ((const float4*)b2)[f4];
  float dc = dis[node];
  int j0 = offS[node], j1 = offE[node];
  int j = j0;
  for (; j + 3 < j1; j += 4) {
    unsigned u0 = sedge[j], u1 = sedge[j + 1];
    unsigned u2 = sedge[j + 2], u3 = sedge[j + 3];
    unsigned s0 = u0 >> 16, s1 = u1 >> 16, s2 = u2 >> 16, s3 = u3 >> 16;
    uint2 r0 = Hh[(size_t)s0 * 16 + f4];
    uint2 r1 = Hh[(size_t)s1 * 16 + f4];
    uint2 r2 = Hh[(size_t)s2 * 16 + f4];
    uint2 r3 = Hh[(size_t)s3 * 16 + f4];
    float n0 = dis[s0] * __half2float(__ushort_as_half((unsigned short)(u0 & 0xFFFFu))) * dc;
    float n1 = dis[s1] * __half2float(__ushort_as_half((unsigned short)(u1 & 0xFFFFu))) * dc;
    float n2 = dis[s2] * __half2float(__ushort_as_half((unsigned short)(u2 & 0xFFFFu))) * dc;
    float n3 = dis[s3] * __half2float(__ushort_as_half((unsigned short)(u3 & 0xFFFFu))) * dc;
    float2 a0 = __half22float2(*(__half2*)&r0.x);
    float2 c0 = __half22float2(*(__half2*)&r0.y);
    float2 a1 = __half22float2(*(__half2*)&r1.x);
    float2 c1 = __half22float2(*(__half2*)&r1.y);
    float2 a2 = __half22float2(*(__half2*)&r2.x);
    float2 c2 = __half22float2(*(__half2*)&r2.y);
    float2 a3 = __half22float2(*(__half2*)&r3.x);
    float2 c3 = __half22float2(*(__half2*)&r3.y);
    acc.x = fmaf(a0.x, n0, acc.x); acc.y = fmaf(a0.y, n0, acc.y);
    acc.z = fmaf(c0.x, n0, acc.z); acc.w = fmaf(c0.y, n0, acc.w);
    acc.x = fmaf(a1.x, n1, acc.x); acc.y = fmaf(a1.y, n1, acc.y);
    acc.z = fmaf(c1.x, n1, acc.z); acc.w = fmaf(c1.y, n1, acc.w);
    acc.x = fmaf(a2.x, n2, acc.x); acc.y = fmaf(a2.y, n2, acc.y);
    acc.z = fmaf(c2.x, n2, acc.z); acc.w = fmaf(c2.y, n2, acc.w);
    acc.x = fmaf(a3.x, n3, acc.x); acc.y = fmaf(a3.y, n3, acc.y);
    acc.z = fmaf(c3.x, n3, acc.z); acc.w = fmaf(c3.y, n3, acc.w);
  }
  for (; j < j1; ++j) {
    unsigned u = sedge[j];
    unsigned s = u >> 16;
    uint2 r = Hh[(size_t)s * 16 + f4];
    float nm = dis[s] * __half2float(__ushort_as_half((unsigned short)(u & 0xFFFFu))) * dc;
    float2 a = __half22float2(*(__half2*)&r.x);
    float2 b = __half22float2(*(__half2*)&r.y);
    acc.x = fmaf(a.x, nm, acc.x); acc.y = fmaf(a.y, nm, acc.y);
    acc.z = fmaf(b.x, nm, acc.z); acc.w = fmaf(b.y, nm, acc.w);
  }
  ((float4*)O)[(size_t)node * 16 + f4] = acc;
}

__global__ void k_final(float* __restrict__ O, const float* __restrict__ sum2,
                        const float* __restrict__ sq2, const float* __restrict__ g2,
                        const float* __restrict__ be2) {
  int i = blockIdx.x * 256 + threadIdx.x;
  if (i < NN * 64) {
    int f = i & 63;
    float mu = sum2[f] * (1.0f / NN);
    float var = sq2[f] * (1.0f / NN) - mu * mu;
    float a = g2[f] * rsqrtf(var + EPSB);
    float c = be2[f] - mu * a;
    O[i] = fmaf(a, O[i], c);
  }
}

extern "C" void kernel_launch(void* const* d_in, const int* in_sizes, int n_in,
                              void* d_out, int out_size, void* d_ws, size_t ws_size,
                              hipStream_t stream) {
  const int* adj = (const int*)d_in[0];
  const float* w = (const float*)d_in[1];
  const float* X = (const float*)d_in[2];
  const float* W1 = (const float*)d_in[3];
  const float* b1 = (const float*)d_in[4];
  const float* g1 = (const float*)d_in[5];
  const float* be1 = (const float*)d_in[6];
  const float* W2 = (const float*)d_in[7];
  const float* b2 = (const float*)d_in[8];
  const float* g2 = (const float*)d_in[9];
  const float* be2 = (const float*)d_in[10];
  float* ws = (float*)d_ws;
  float* out = (float*)d_out;

  unsigned* sedge = (unsigned*)(ws + W_SEDGE);
  int* offS = (int*)(ws + W_OFFS);
  int* offE = (int*)(ws + W_OFFE);
  float* dis = ws + W_DIS;
  int* cnt_g = (int*)(ws + W_CNTG);
  float* sum1 = ws + W_SUM1;
  float* sq1 = ws + W_SQ1;
  float* sum2 = ws + W_SUM2;
  float* sq2 = ws + W_SQ2;
  int2* temp = (int2*)(ws + W_TEMP);
  __half* H1h = (__half*)(ws + W_H1);
  __half* H2h = (__half*)(ws + W_H1);  // aliases H1 (dead after gather1)
  __half* O1h = (__half*)(ws + W_O1);

  // zero bucket cursors + BN stats (one contiguous range)
  hipMemsetAsync(cnt_g, 0, (size_t)(W_SQ2 + 64 - W_CNTG) * sizeof(float), stream);

  k_scatC2<<<CB, 256, 0, stream>>>(adj, w, cnt_g, temp);
  k_binD2<<<NBKT, 256, 0, stream>>>(temp, cnt_g, dis, offS, offE, sedge);

  k_gemm1m<<<(NN + 63) / 64, 256, 0, stream>>>(X, W1, H1h);
  k_gather1<<<NN / 8, 256, 0, stream>>>(offS, offE, sedge, dis, H1h, b1, O1h);
  k_statsh<<<512, 256, 0, stream>>>(O1h, sum1, sq1);

  k_gemm2m<<<(NN + 63) / 64, 256, 0, stream>>>(O1h, W2, sum1, sq1, g1, be1, H2h);
  k_gather2<<<NN / 16, 256, 0, stream>>>(offS, offE, sedge, dis, H2h, b2, out);
  k_stats<<<512, 256, 0, stream>>>(out, sum2, sq2, 64);
  k_final<<<NN * 64 / 256, 256, 0, stream>>>(out, sum2, sq2, g2, be2);
}